// Round 6
// baseline (339.672 us; speedup 1.0000x reference)
//
#include <hip/hip_runtime.h>
#include <math.h>

// Problem constants (MambaBlock reference)
#define BB 2
#define LL 1024
#define DM 1024
#define DI 1024
#define DS 16
#define ROWS (BB * LL)   // 2048
#define CH 16            // scan chunk length
#define NCH (LL / CH)    // 64 chunks
#define NP 1088          // fused GEMM N: 1024 Delta + 16 B + 16 C + 32 zero pad

typedef unsigned short ushort_t;
typedef __attribute__((ext_vector_type(8))) short short8;
typedef __attribute__((ext_vector_type(4))) float f32x4;
typedef __attribute__((ext_vector_type(4))) float f4;
typedef __attribute__((ext_vector_type(4))) ushort_t us4;

static __device__ __forceinline__ float sp_f(float x) {
    return fmaxf(x, 0.f) + log1pf(expf(-fabsf(x)));
}
static __device__ __forceinline__ ushort_t f2bf(float f) {
    unsigned u = __float_as_uint(f);
    u += 0x7fffu + ((u >> 16) & 1u);
    return (ushort_t)(u >> 16);
}
static __device__ __forceinline__ float bf2f(ushort_t s) {
    return __uint_as_float(((unsigned)s) << 16);
}

// LDS XOR swizzle (involution: flips addr bits 4,5 keyed by bits 7,8).
// Fragment ds_read_b128 becomes 2-way (free, m136); staging via
// global_load_lds uses linear LDS dest + inverse-swizzled GLOBAL source
// (both-sides rule, §5.5 T21 / m173).
#define SWZ(L) ((L) ^ ((((L) >> 7) & 1) << 4) ^ ((((L) >> 8) & 1) << 5))

static __device__ __forceinline__ void gl_lds16(const void* g, void* l) {
    __builtin_amdgcn_global_load_lds(
        (const __attribute__((address_space(1))) unsigned int*)g,
        (__attribute__((address_space(3))) unsigned int*)l, 16, 0, 0);
}

// ---------------------------------------------------------------------------
// bf16 MFMA GEMM: C[M,N] = epi(A[M,K] @ Bt[N,K]^T), output stride ldc.
// 128xTN tile (TN=128 or 64), BK=32, 256 threads (4 waves 2x2).
// global_load_lds staging (pre-swizzled source), LDS double buffer,
// one barrier per K-step (T3-minimum 2-phase).
// PROJ: cols [DM,DM+DS) -> BpO, [DM+DS,DM+2DS) -> CpO (fp32), other >=DM dropped.
// ---------------------------------------------------------------------------
template <int TN, int ACT, bool HAS_BIAS, bool HAS_RES, bool OUTBF, bool PROJ>
__global__ __launch_bounds__(256) void gemm_bf_k(
    const ushort_t* __restrict__ A, const ushort_t* __restrict__ Bt,
    const float* __restrict__ bias, const float* __restrict__ res,
    void* __restrict__ Cout, float* __restrict__ BpO, float* __restrict__ CpO,
    int M, int N, int K, int ldc)
{
    constexpr int NACC = TN / 32;     // N-frags per wave
    constexpr int BCH = TN / 64;      // 1KB B-staging chunks per wave
    __shared__ __align__(16) char lsa[2][8192];      // A tile [128][32] bf16
    __shared__ __align__(16) char lsb[2][TN * 64];   // B tile [TN][32] bf16

    const int tid = threadIdx.x;
    const int lane = tid & 63;
    const int w = tid >> 6;
    const int wr = w >> 1, wc = w & 1;
    const int row0 = blockIdx.y * 128, col0 = blockIdx.x * TN;
    const int rl = lane & 15, q = lane >> 4;

    // per-lane pre-swizzled global sources (bytes); LDS dest is linear.
    const char* gA[2];
#pragma unroll
    for (int j = 0; j < 2; ++j) {
        int Lc = (w * 2 + j) * 1024 + lane * 16;
        int L = SWZ(Lc);
        gA[j] = (const char*)A + ((size_t)(row0 + (L >> 6)) * K) * 2 + (L & 63);
    }
    const char* gB[BCH];
#pragma unroll
    for (int j = 0; j < BCH; ++j) {
        int Lc = (w * BCH + j) * 1024 + lane * 16;
        int L = SWZ(Lc);
        gB[j] = (const char*)Bt + ((size_t)(col0 + (L >> 6)) * K) * 2 + (L & 63);
    }

    int LA[4], LB[NACC];
#pragma unroll
    for (int m = 0; m < 4; ++m) LA[m] = SWZ((wr * 64 + m * 16 + rl) * 64 + q * 16);
#pragma unroll
    for (int n = 0; n < NACC; ++n)
        LB[n] = SWZ((wc * (TN / 2) + n * 16 + rl) * 64 + q * 16);

    f32x4 acc[4][NACC] = {};
    const int NT = K >> 5;

    // prologue: stage K-tile 0 into buf 0
#pragma unroll
    for (int j = 0; j < 2; ++j) gl_lds16(gA[j], &lsa[0][(w * 2 + j) * 1024]);
#pragma unroll
    for (int j = 0; j < BCH; ++j) gl_lds16(gB[j], &lsb[0][(w * BCH + j) * 1024]);
    __syncthreads();   // drains vmcnt(0): tile 0 resident

    int cur = 0;
    for (int kt = 0; kt < NT; ++kt) {
        if (kt + 1 < NT) {   // async issue of next tile; hides under MFMA
            const int kb = (kt + 1) * 64;
#pragma unroll
            for (int j = 0; j < 2; ++j)
                gl_lds16(gA[j] + kb, &lsa[cur ^ 1][(w * 2 + j) * 1024]);
#pragma unroll
            for (int j = 0; j < BCH; ++j)
                gl_lds16(gB[j] + kb, &lsb[cur ^ 1][(w * BCH + j) * 1024]);
        }
        short8 af[4], bfr[NACC];
#pragma unroll
        for (int m = 0; m < 4; ++m) af[m] = *(const short8*)(&lsa[cur][LA[m]]);
#pragma unroll
        for (int n = 0; n < NACC; ++n) bfr[n] = *(const short8*)(&lsb[cur][LB[n]]);
#pragma unroll
        for (int m = 0; m < 4; ++m)
#pragma unroll
            for (int n = 0; n < NACC; ++n)
                acc[m][n] = __builtin_amdgcn_mfma_f32_16x16x32_bf16(
                    af[m], bfr[n], acc[m][n], 0, 0, 0);
        __syncthreads();   // all reads of buf[cur] done; next tile resident
        cur ^= 1;
    }

    float bia[NACC];
#pragma unroll
    for (int n = 0; n < NACC; ++n) {
        int c = col0 + wc * (TN / 2) + n * 16 + rl;
        bia[n] = (HAS_BIAS && c < DM) ? bias[c] : 0.f;
    }
#pragma unroll
    for (int m = 0; m < 4; ++m) {
#pragma unroll
        for (int n = 0; n < NACC; ++n) {
            int c = col0 + wc * (TN / 2) + n * 16 + rl;
#pragma unroll
            for (int i = 0; i < 4; ++i) {
                int r = row0 + wr * 64 + m * 16 + q * 4 + i;
                float v = acc[m][n][i];
                if (PROJ && c >= DM) {
                    if (c < DM + DS)          BpO[(size_t)r * DS + (c - DM)] = v;
                    else if (c < DM + 2 * DS) CpO[(size_t)r * DS + (c - DM - DS)] = v;
                } else {
                    v += bia[n];
                    if (ACT == 1) v = sp_f(v);
                    if (HAS_RES) v += res[(size_t)r * ldc + c];
                    if (OUTBF) ((ushort_t*)Cout)[(size_t)r * ldc + c] = f2bf(v);
                    else       ((float*)Cout)[(size_t)r * ldc + c] = v;
                }
            }
        }
    }
}

// ---------------------------------------------------------------------------
// Transpose-convert: in[K][N] fp32 -> out[N][K] bf16
// ---------------------------------------------------------------------------
__global__ __launch_bounds__(256) void tconv_k(
    const float* __restrict__ in, ushort_t* __restrict__ out, int K, int N)
{
    __shared__ float t[32][33];
    int lx = threadIdx.x & 31, ly = threadIdx.x >> 5;
    int n0 = blockIdx.x * 32, k0 = blockIdx.y * 32;
#pragma unroll
    for (int i = 0; i < 32; i += 8)
        t[ly + i][lx] = in[(size_t)(k0 + ly + i) * N + n0 + lx];
    __syncthreads();
#pragma unroll
    for (int i = 0; i < 32; i += 8)
        out[(size_t)(n0 + ly + i) * K + k0 + lx] = f2bf(t[lx][ly + i]);
}

// rows [DM, DM+64) of WdcT: W_B^T (16), W_C^T (16), zeros (32)
__global__ __launch_bounds__(256) void tail_pack_k(
    const float* __restrict__ WB, const float* __restrict__ WC,
    ushort_t* __restrict__ WdcT)
{
    int t = blockIdx.x * 256 + threadIdx.x;   // 64*1024
    int k = t & (DM - 1);
    int r = t >> 10;                          // 0..63
    ushort_t v = 0;
    if (r < DS)          v = f2bf(WB[(size_t)k * DS + r]);
    else if (r < 2 * DS) v = f2bf(WC[(size_t)k * DS + (r - DS)]);
    WdcT[(size_t)(DM + r) * DM + k] = v;
}

// fused bias: b2[n] = sum_m delta_base[m] * W_tau[m][n]
__global__ __launch_bounds__(256) void bias2_k(
    const float* __restrict__ db, const float* __restrict__ Wt,
    float* __restrict__ b2)
{
    int n = blockIdx.x * 256 + threadIdx.x;   // 1024
    float s = 0.f;
#pragma unroll 4
    for (int m = 0; m < DM; ++m) s = fmaf(db[m], Wt[(size_t)m * DM + n], s);
    b2[n] = s;
}

// elementwise fp32 -> bf16 (4/thread)
__global__ __launch_bounds__(256) void cvt_bf_k(
    const float* __restrict__ in, ushort_t* __restrict__ out)
{
    int t = blockIdx.x * 256 + threadIdx.x;
    f4 v = ((const f4*)in)[t];
    us4 o;
    o.x = f2bf(v.x); o.y = f2bf(v.y); o.z = f2bf(v.z); o.w = f2bf(v.w);
    ((us4*)out)[t] = o;
}

// ---------------------------------------------------------------------------
// Depthwise conv1d (K=3, same padding) + SiLU.  bf16 in (z), bf16 out (val).
// ---------------------------------------------------------------------------
__global__ __launch_bounds__(256) void conv_silu_k(
    const ushort_t* __restrict__ z_bf, const float* __restrict__ cw,
    ushort_t* __restrict__ val_bf)
{
    int t = blockIdx.x * 256 + threadIdx.x;    // ROWS*DI/4
    int c0 = (t & 255) * 4;
    int row = t >> 8;
    int l = row & (LL - 1);
    const ushort_t* zr = z_bf + (size_t)row * (2 * DI) + c0;
    us4 zz = {0, 0, 0, 0};
    us4 vm = (l > 0)      ? *(const us4*)(zr - 2 * DI) : zz;
    us4 v0 = *(const us4*)(zr);
    us4 vp = (l < LL - 1) ? *(const us4*)(zr + 2 * DI) : zz;
    const f4* wp = (const f4*)(cw + (size_t)c0 * 3);
    f4 w0 = wp[0], w1 = wp[1], w2 = wp[2];
    float w[12];
#pragma unroll
    for (int k = 0; k < 4; ++k) { w[k] = w0[k]; w[4 + k] = w1[k]; w[8 + k] = w2[k]; }
    us4 o;
#pragma unroll
    for (int j = 0; j < 4; ++j) {
        float s = bf2f(vm[j]) * w[3 * j] + bf2f(v0[j]) * w[3 * j + 1]
                + bf2f(vp[j]) * w[3 * j + 2];
        float si = s / (1.f + __expf(-s));
        o[j] = f2bf(si);
    }
    *(us4*)(val_bf + (size_t)row * DI + c0) = o;
}

// ---------------------------------------------------------------------------
// Chunked selective scan, thread per (b,d,chunk), 16 n in registers.
// h = a*(h+t) - t with t = (B/A)*u;  a = exp(Delta*A).
// ---------------------------------------------------------------------------
__global__ __launch_bounds__(256) void scan_p1_k(
    const ushort_t* __restrict__ Del_bf, const ushort_t* __restrict__ val_bf,
    const float* __restrict__ Bp, const float* __restrict__ A_log,
    float* __restrict__ aprod, float* __restrict__ hloc)
{
    int t = blockIdx.x * 256 + threadIdx.x;    // BB*NCH*DI = 131072
    int d = t & (DI - 1);
    int c = (t >> 10) & (NCH - 1);
    int b = t >> 16;

    float Adn[DS], ci[DS];
    const f4* alp = (const f4*)(A_log + (size_t)d * DS);
#pragma unroll
    for (int j = 0; j < 4; ++j) {
        f4 al = alp[j];
#pragma unroll
        for (int k = 0; k < 4; ++k) {
            float a = -__expf(al[k]);
            Adn[j * 4 + k] = a;
            ci[j * 4 + k] = 1.0f / a;
        }
    }
    int row0 = b * LL + c * CH;
    const ushort_t* Dp = Del_bf + (size_t)row0 * DI + d;
    const ushort_t* up = val_bf + (size_t)row0 * DI + d;
    const f4* bp = (const f4*)(Bp + (size_t)row0 * DS);

    float h[DS];
#pragma unroll
    for (int n = 0; n < DS; ++n) h[n] = 0.f;
    float sdv = 0.f;

#pragma unroll 2
    for (int l = 0; l < CH; ++l) {
        float dv = bf2f(Dp[(size_t)l * DI]);
        float u  = bf2f(up[(size_t)l * DI]);
        f4 q0 = bp[l * 4 + 0], q1 = bp[l * 4 + 1], q2 = bp[l * 4 + 2], q3 = bp[l * 4 + 3];
        float bn[DS];
#pragma unroll
        for (int k = 0; k < 4; ++k) {
            bn[k] = q0[k]; bn[4 + k] = q1[k]; bn[8 + k] = q2[k]; bn[12 + k] = q3[k];
        }
        sdv += dv;
#pragma unroll
        for (int n = 0; n < DS; ++n) {
            float a  = __expf(dv * Adn[n]);
            float tt = (ci[n] * bn[n]) * u;
            float s  = h[n] + tt;
            h[n] = fmaf(a, s, -tt);
        }
    }
    size_t o = (((size_t)b * NCH + c) * DI + d) * DS;
#pragma unroll
    for (int j = 0; j < 4; ++j) {
        f4 hv, av;
#pragma unroll
        for (int k = 0; k < 4; ++k) {
            hv[k] = h[j * 4 + k];
            av[k] = __expf(sdv * Adn[j * 4 + k]);
        }
        *(f4*)(hloc + o + j * 4) = hv;
        *(f4*)(aprod + o + j * 4) = av;
    }
}

__global__ __launch_bounds__(256) void scan_p2_k(
    const float* __restrict__ aprod, const float* __restrict__ hloc,
    float* __restrict__ hin)
{
    int t = blockIdx.x * 256 + threadIdx.x;    // BB*DI*DS = 32768
    int dn = t & (DI * DS - 1);
    int b = t >> 14;
    float h = 0.f;
    size_t base = (size_t)b * NCH * DI * DS + dn;
#pragma unroll 4
    for (int c = 0; c < NCH; ++c) {
        size_t idx = base + (size_t)c * (DI * DS);
        hin[idx] = h;
        h = fmaf(aprod[idx], h, hloc[idx]);
    }
}

// phase 3: recompute with correct h_in; fused gate: g_bf = bf16(y * silu(zgate))
__global__ __launch_bounds__(256) void scan_p3_k(
    const ushort_t* __restrict__ Del_bf, const ushort_t* __restrict__ val_bf,
    const float* __restrict__ Bp, const float* __restrict__ Cp,
    const float* __restrict__ A_log, const float* __restrict__ hin,
    const ushort_t* __restrict__ z_bf, ushort_t* __restrict__ g_bf)
{
    int t = blockIdx.x * 256 + threadIdx.x;    // BB*NCH*DI
    int d = t & (DI - 1);
    int c = (t >> 10) & (NCH - 1);
    int b = t >> 16;

    float Adn[DS], ci[DS];
    const f4* alp = (const f4*)(A_log + (size_t)d * DS);
#pragma unroll
    for (int j = 0; j < 4; ++j) {
        f4 al = alp[j];
#pragma unroll
        for (int k = 0; k < 4; ++k) {
            float a = -__expf(al[k]);
            Adn[j * 4 + k] = a;
            ci[j * 4 + k] = 1.0f / a;
        }
    }
    int row0 = b * LL + c * CH;
    const ushort_t* Dp = Del_bf + (size_t)row0 * DI + d;
    const ushort_t* up = val_bf + (size_t)row0 * DI + d;
    const ushort_t* zp = z_bf + (size_t)row0 * (2 * DI) + DI + d;
    const f4* bp = (const f4*)(Bp + (size_t)row0 * DS);
    const f4* cp = (const f4*)(Cp + (size_t)row0 * DS);
    ushort_t* gp = g_bf + (size_t)row0 * DI + d;

    float h[DS];
    size_t o = (((size_t)b * NCH + c) * DI + d) * DS;
#pragma unroll
    for (int j = 0; j < 4; ++j) {
        f4 hv = *(const f4*)(hin + o + j * 4);
#pragma unroll
        for (int k = 0; k < 4; ++k) h[j * 4 + k] = hv[k];
    }

#pragma unroll 2
    for (int l = 0; l < CH; ++l) {
        float dv = bf2f(Dp[(size_t)l * DI]);
        float u  = bf2f(up[(size_t)l * DI]);
        f4 q0 = bp[l * 4 + 0], q1 = bp[l * 4 + 1], q2 = bp[l * 4 + 2], q3 = bp[l * 4 + 3];
        f4 r0 = cp[l * 4 + 0], r1 = cp[l * 4 + 1], r2 = cp[l * 4 + 2], r3 = cp[l * 4 + 3];
        float bn[DS], cn[DS];
#pragma unroll
        for (int k = 0; k < 4; ++k) {
            bn[k] = q0[k]; bn[4 + k] = q1[k]; bn[8 + k] = q2[k]; bn[12 + k] = q3[k];
            cn[k] = r0[k]; cn[4 + k] = r1[k]; cn[8 + k] = r2[k]; cn[12 + k] = r3[k];
        }
        float psum = 0.f;
#pragma unroll
        for (int n = 0; n < DS; ++n) {
            float a  = __expf(dv * Adn[n]);
            float tt = (ci[n] * bn[n]) * u;
            float s  = h[n] + tt;
            h[n] = fmaf(a, s, -tt);
            psum = fmaf(h[n], cn[n], psum);
        }
        float zg = bf2f(zp[(size_t)l * 2 * DI]);
        float si = zg / (1.f + __expf(-zg));
        gp[(size_t)l * DI] = f2bf(psum * si);
    }
}

// ---------------------------------------------------------------------------
extern "C" void kernel_launch(void* const* d_in, const int* in_sizes, int n_in,
                              void* d_out, int out_size, void* d_ws, size_t ws_size,
                              hipStream_t stream)
{
    (void)in_sizes; (void)n_in; (void)out_size; (void)ws_size;

    const float* x        = (const float*)d_in[0];
    const float* W_in     = (const float*)d_in[1];
    const float* conv_w   = (const float*)d_in[2];
    const float* W_B      = (const float*)d_in[3];
    const float* W_C      = (const float*)d_in[4];
    const float* W_delta  = (const float*)d_in[5];
    const float* delta_b  = (const float*)d_in[6];
    const float* W_tau    = (const float*)d_in[7];
    const float* A_log    = (const float*)d_in[8];
    const float* W_out    = (const float*)d_in[9];
    float* out = (float*)d_out;

    const size_t M1 = 1024 * 1024;
    ushort_t* us = (ushort_t*)d_ws;
    ushort_t* z_bf   = us;                    // 4M ushort
    ushort_t* val_bf = us + 4 * M1;           // 2M
    ushort_t* Del_bf = us + 6 * M1;           // 2M
    ushort_t* x_bf   = us + 8 * M1;           // 2M
    ushort_t* g_bf   = us + 10 * M1;          // 2M
    ushort_t* WinT   = us + 12 * M1;          // 2M
    ushort_t* WoT    = us + 14 * M1;          // 1M
    ushort_t* WtT    = us + 15 * M1;          // 1M
    ushort_t* Wd_bf  = us + 16 * M1;          // 1M
    ushort_t* WdcT   = us + 17 * M1;          // NP*1024 = 1.0625M (~36.1MB end)
    float* fb    = (float*)(us + 20 * M1);    // 40MB offset
    float* Bp    = fb;                         // 32768
    float* Cp    = fb + (size_t)ROWS * DS;     // 32768
    float* bias2 = fb + 2 * (size_t)ROWS * DS; // 1024
    float* aprod = bias2 + 1024;               // 2M fl
    float* hloc  = aprod + 2 * M1;             // 2M fl
    float* hin   = hloc + 2 * M1;              // 2M fl (~64.3MB end)

    // 0) converts / weight prep
    cvt_bf_k<<<(ROWS * DM / 4) / 256, 256, 0, stream>>>(x, x_bf);
    cvt_bf_k<<<(DI * DM / 4) / 256, 256, 0, stream>>>(W_delta, Wd_bf);
    tconv_k<<<dim3(2 * DI / 32, DM / 32), 256, 0, stream>>>(W_in, WinT, DM, 2 * DI);
    tconv_k<<<dim3(DM / 32, DM / 32), 256, 0, stream>>>(W_tau, WtT, DM, DM);
    tconv_k<<<dim3(DM / 32, DI / 32), 256, 0, stream>>>(W_out, WoT, DI, DM);
    tail_pack_k<<<(64 * DM) / 256, 256, 0, stream>>>(W_B, W_C, WdcT);
    bias2_k<<<DM / 256, 256, 0, stream>>>(delta_b, W_tau, bias2);

    // 0b) fused weight: WdcT[n][i] = (W_delta @ W_tau)^T = W_tau^T @ W_delta^T
    gemm_bf_k<64, 0, false, false, true, false><<<dim3(DM / 64, DI / 128), 256, 0, stream>>>(
        WtT, Wd_bf, nullptr, nullptr, WdcT, nullptr, nullptr, DM, DI, DM, DM);

    // 1) z = x @ W_in  (bf16 out)
    gemm_bf_k<128, 0, false, false, true, false><<<dim3(2 * DI / 128, ROWS / 128), 256, 0, stream>>>(
        x_bf, WinT, nullptr, nullptr, z_bf, nullptr, nullptr, ROWS, 2 * DI, DM, 2 * DI);

    // 2) val = silu(conv1d(z[:, :DI]))
    conv_silu_k<<<(ROWS * DI / 4) / 256, 256, 0, stream>>>(z_bf, conv_w, val_bf);

    // 3) Delta = softplus(val @ Wfused + bias2) -> Del_bf; fused B/C proj -> Bp,Cp
    gemm_bf_k<64, 1, true, false, true, true><<<dim3(NP / 64, ROWS / 128), 256, 0, stream>>>(
        val_bf, WdcT, bias2, nullptr, Del_bf, Bp, Cp, ROWS, NP, DI, DM);

    // 4) chunked selective scan; p3 fuses gate -> g_bf
    scan_p1_k<<<(BB * NCH * DI) / 256, 256, 0, stream>>>(
        Del_bf, val_bf, Bp, A_log, aprod, hloc);
    scan_p2_k<<<(BB * DI * DS) / 256, 256, 0, stream>>>(aprod, hloc, hin);
    scan_p3_k<<<(BB * NCH * DI) / 256, 256, 0, stream>>>(
        Del_bf, val_bf, Bp, Cp, A_log, hin, z_bf, g_bf);

    // 5) out = g @ W_out + x (fp32 out)
    gemm_bf_k<64, 0, false, true, false, false><<<dim3(DM / 64, ROWS / 128), 256, 0, stream>>>(
        g_bf, WoT, nullptr, x, out, nullptr, nullptr, ROWS, DM, DI, DM);
}

// Round 7
// 254.963 us; speedup vs baseline: 1.3322x; 1.3322x over previous
//
#include <hip/hip_runtime.h>
#include <math.h>

// Problem constants (MambaBlock reference)
#define BB 2
#define LL 1024
#define DM 1024
#define DI 1024
#define DS 16
#define ROWS (BB * LL)   // 2048
#define CH 16            // scan chunk length
#define NCH (LL / CH)    // 64 chunks
#define NP 1088          // fused GEMM N: 1024 Delta + 16 B + 16 C + 32 zero pad

typedef unsigned short ushort_t;
typedef __attribute__((ext_vector_type(8))) short short8;
typedef __attribute__((ext_vector_type(4))) float f32x4;
typedef __attribute__((ext_vector_type(4))) float f4;
typedef __attribute__((ext_vector_type(4))) ushort_t us4;

static __device__ __forceinline__ float sp_f(float x) {
    return fmaxf(x, 0.f) + log1pf(expf(-fabsf(x)));
}
static __device__ __forceinline__ ushort_t f2bf(float f) {
    unsigned u = __float_as_uint(f);
    u += 0x7fffu + ((u >> 16) & 1u);
    return (ushort_t)(u >> 16);
}
static __device__ __forceinline__ float bf2f(ushort_t s) {
    return __uint_as_float(((unsigned)s) << 16);
}

// LDS XOR swizzle (involution: flips addr bits 4,5 keyed by bits 7,8).
#define SWZ(L) ((L) ^ ((((L) >> 7) & 1) << 4) ^ ((((L) >> 8) & 1) << 5))

static __device__ __forceinline__ void gl_lds16(const void* g, void* l) {
    __builtin_amdgcn_global_load_lds(
        (const __attribute__((address_space(1))) unsigned int*)g,
        (__attribute__((address_space(3))) unsigned int*)l, 16, 0, 0);
}

// ---------------------------------------------------------------------------
// bf16 MFMA GEMM: C[M,N] = epi(A[M,K] @ Bt[N,K]^T), output stride ldc.
// 128xTN tile (TN=128 or 64), BK=32, 256 threads (4 waves 2x2).
// global_load_lds staging (pre-swizzled source), LDS double buffer,
// one barrier per K-step (T3-minimum 2-phase).
// PROJ: cols [DM,DM+DS) -> BpO, [DM+DS,DM+2DS) -> CpO (fp32), other >=DM dropped.
// ---------------------------------------------------------------------------
template <int TN, int ACT, bool HAS_BIAS, bool HAS_RES, bool OUTBF, bool PROJ>
__global__ __launch_bounds__(256) void gemm_bf_k(
    const ushort_t* __restrict__ A, const ushort_t* __restrict__ Bt,
    const float* __restrict__ bias, const float* __restrict__ res,
    void* __restrict__ Cout, float* __restrict__ BpO, float* __restrict__ CpO,
    int M, int N, int K, int ldc)
{
    constexpr int NACC = TN / 32;     // N-frags per wave
    constexpr int BCH = TN / 64;      // 1KB B-staging chunks per wave
    __shared__ __align__(16) char lsa[2][8192];      // A tile [128][32] bf16
    __shared__ __align__(16) char lsb[2][TN * 64];   // B tile [TN][32] bf16

    const int tid = threadIdx.x;
    const int lane = tid & 63;
    const int w = tid >> 6;
    const int wr = w >> 1, wc = w & 1;
    const int row0 = blockIdx.y * 128, col0 = blockIdx.x * TN;
    const int rl = lane & 15, q = lane >> 4;

    // per-lane pre-swizzled global sources (bytes); LDS dest is linear.
    const char* gA[2];
#pragma unroll
    for (int j = 0; j < 2; ++j) {
        int Lc = (w * 2 + j) * 1024 + lane * 16;
        int L = SWZ(Lc);
        gA[j] = (const char*)A + ((size_t)(row0 + (L >> 6)) * K) * 2 + (L & 63);
    }
    const char* gB[BCH];
#pragma unroll
    for (int j = 0; j < BCH; ++j) {
        int Lc = (w * BCH + j) * 1024 + lane * 16;
        int L = SWZ(Lc);
        gB[j] = (const char*)Bt + ((size_t)(col0 + (L >> 6)) * K) * 2 + (L & 63);
    }

    int LA[4], LB[NACC];
#pragma unroll
    for (int m = 0; m < 4; ++m) LA[m] = SWZ((wr * 64 + m * 16 + rl) * 64 + q * 16);
#pragma unroll
    for (int n = 0; n < NACC; ++n)
        LB[n] = SWZ((wc * (TN / 2) + n * 16 + rl) * 64 + q * 16);

    f32x4 acc[4][NACC] = {};
    const int NT = K >> 5;

    // prologue: stage K-tile 0 into buf 0
#pragma unroll
    for (int j = 0; j < 2; ++j) gl_lds16(gA[j], &lsa[0][(w * 2 + j) * 1024]);
#pragma unroll
    for (int j = 0; j < BCH; ++j) gl_lds16(gB[j], &lsb[0][(w * BCH + j) * 1024]);
    __syncthreads();   // drains vmcnt(0): tile 0 resident

    int cur = 0;
    for (int kt = 0; kt < NT; ++kt) {
        if (kt + 1 < NT) {   // async issue of next tile; hides under MFMA
            const int kb = (kt + 1) * 64;
#pragma unroll
            for (int j = 0; j < 2; ++j)
                gl_lds16(gA[j] + kb, &lsa[cur ^ 1][(w * 2 + j) * 1024]);
#pragma unroll
            for (int j = 0; j < BCH; ++j)
                gl_lds16(gB[j] + kb, &lsb[cur ^ 1][(w * BCH + j) * 1024]);
        }
        short8 af[4], bfr[NACC];
#pragma unroll
        for (int m = 0; m < 4; ++m) af[m] = *(const short8*)(&lsa[cur][LA[m]]);
#pragma unroll
        for (int n = 0; n < NACC; ++n) bfr[n] = *(const short8*)(&lsb[cur][LB[n]]);
#pragma unroll
        for (int m = 0; m < 4; ++m)
#pragma unroll
            for (int n = 0; n < NACC; ++n)
                acc[m][n] = __builtin_amdgcn_mfma_f32_16x16x32_bf16(
                    af[m], bfr[n], acc[m][n], 0, 0, 0);
        __syncthreads();   // all reads of buf[cur] done; next tile resident
        cur ^= 1;
    }

    float bia[NACC];
#pragma unroll
    for (int n = 0; n < NACC; ++n) {
        int c = col0 + wc * (TN / 2) + n * 16 + rl;
        bia[n] = (HAS_BIAS && c < DM) ? bias[c] : 0.f;
    }
#pragma unroll
    for (int m = 0; m < 4; ++m) {
#pragma unroll
        for (int n = 0; n < NACC; ++n) {
            int c = col0 + wc * (TN / 2) + n * 16 + rl;
#pragma unroll
            for (int i = 0; i < 4; ++i) {
                int r = row0 + wr * 64 + m * 16 + q * 4 + i;
                float v = acc[m][n][i];
                if (PROJ && c >= DM) {
                    if (c < DM + DS)          BpO[(size_t)r * DS + (c - DM)] = v;
                    else if (c < DM + 2 * DS) CpO[(size_t)r * DS + (c - DM - DS)] = v;
                } else {
                    v += bia[n];
                    if (ACT == 1) v = sp_f(v);
                    if (HAS_RES) v += res[(size_t)r * ldc + c];
                    if (OUTBF) ((ushort_t*)Cout)[(size_t)r * ldc + c] = f2bf(v);
                    else       ((float*)Cout)[(size_t)r * ldc + c] = v;
                }
            }
        }
    }
}

// ---------------------------------------------------------------------------
// Transpose-convert: in[K][N] fp32 -> out[N][K] bf16
// ---------------------------------------------------------------------------
__global__ __launch_bounds__(256) void tconv_k(
    const float* __restrict__ in, ushort_t* __restrict__ out, int K, int N)
{
    __shared__ float t[32][33];
    int lx = threadIdx.x & 31, ly = threadIdx.x >> 5;
    int n0 = blockIdx.x * 32, k0 = blockIdx.y * 32;
#pragma unroll
    for (int i = 0; i < 32; i += 8)
        t[ly + i][lx] = in[(size_t)(k0 + ly + i) * N + n0 + lx];
    __syncthreads();
#pragma unroll
    for (int i = 0; i < 32; i += 8)
        out[(size_t)(n0 + ly + i) * K + k0 + lx] = f2bf(t[lx][ly + i]);
}

// rows [DM, DM+64) of WdcT: W_B^T (16), W_C^T (16), zeros (32)
__global__ __launch_bounds__(256) void tail_pack_k(
    const float* __restrict__ WB, const float* __restrict__ WC,
    ushort_t* __restrict__ WdcT)
{
    int t = blockIdx.x * 256 + threadIdx.x;   // 64*1024
    int k = t & (DM - 1);
    int r = t >> 10;                          // 0..63
    ushort_t v = 0;
    if (r < DS)          v = f2bf(WB[(size_t)k * DS + r]);
    else if (r < 2 * DS) v = f2bf(WC[(size_t)k * DS + (r - DS)]);
    WdcT[(size_t)(DM + r) * DM + k] = v;
}

// fused bias: b2[n] = dot(WtT[n][:], db).  Wave per column (coalesced 2KB row).
__global__ __launch_bounds__(256) void bias2_k(
    const float* __restrict__ db, const ushort_t* __restrict__ WtT,
    float* __restrict__ b2)
{
    int lane = threadIdx.x & 63;
    int wv = threadIdx.x >> 6;
    int n = blockIdx.x * 4 + wv;               // 256 blocks x 4 waves = 1024
    const ushort_t* wr = WtT + (size_t)n * DM + lane * 16;
    short8 a0 = *(const short8*)(wr);
    short8 a1 = *(const short8*)(wr + 8);
    const f4* dp = (const f4*)(db + lane * 16);
    f4 d0 = dp[0], d1 = dp[1], d2 = dp[2], d3 = dp[3];
    float s = 0.f;
#pragma unroll
    for (int j = 0; j < 4; ++j) {
        s = fmaf(bf2f((ushort_t)a0[j]),     d0[j], s);
        s = fmaf(bf2f((ushort_t)a0[j + 4]), d1[j], s);
        s = fmaf(bf2f((ushort_t)a1[j]),     d2[j], s);
        s = fmaf(bf2f((ushort_t)a1[j + 4]), d3[j], s);
    }
#pragma unroll
    for (int off = 1; off < 64; off <<= 1) s += __shfl_xor(s, off);
    if (lane == 0) b2[n] = s;
}

// elementwise fp32 -> bf16 (4/thread)
__global__ __launch_bounds__(256) void cvt_bf_k(
    const float* __restrict__ in, ushort_t* __restrict__ out)
{
    int t = blockIdx.x * 256 + threadIdx.x;
    f4 v = ((const f4*)in)[t];
    us4 o;
    o.x = f2bf(v.x); o.y = f2bf(v.y); o.z = f2bf(v.z); o.w = f2bf(v.w);
    ((us4*)out)[t] = o;
}

// ---------------------------------------------------------------------------
// Depthwise conv1d (K=3, same padding) + SiLU.  bf16 in (z), bf16 out (val).
// ---------------------------------------------------------------------------
__global__ __launch_bounds__(256) void conv_silu_k(
    const ushort_t* __restrict__ z_bf, const float* __restrict__ cw,
    ushort_t* __restrict__ val_bf)
{
    int t = blockIdx.x * 256 + threadIdx.x;    // ROWS*DI/4
    int c0 = (t & 255) * 4;
    int row = t >> 8;
    int l = row & (LL - 1);
    const ushort_t* zr = z_bf + (size_t)row * (2 * DI) + c0;
    us4 zz = {0, 0, 0, 0};
    us4 vm = (l > 0)      ? *(const us4*)(zr - 2 * DI) : zz;
    us4 v0 = *(const us4*)(zr);
    us4 vp = (l < LL - 1) ? *(const us4*)(zr + 2 * DI) : zz;
    const f4* wp = (const f4*)(cw + (size_t)c0 * 3);
    f4 w0 = wp[0], w1 = wp[1], w2 = wp[2];
    float w[12];
#pragma unroll
    for (int k = 0; k < 4; ++k) { w[k] = w0[k]; w[4 + k] = w1[k]; w[8 + k] = w2[k]; }
    us4 o;
#pragma unroll
    for (int j = 0; j < 4; ++j) {
        float s = bf2f(vm[j]) * w[3 * j] + bf2f(v0[j]) * w[3 * j + 1]
                + bf2f(vp[j]) * w[3 * j + 2];
        float si = s / (1.f + __expf(-s));
        o[j] = f2bf(si);
    }
    *(us4*)(val_bf + (size_t)row * DI + c0) = o;
}

// ---------------------------------------------------------------------------
// Chunked selective scan, thread per (b,d,chunk), 16 n in registers.
// h = a*(h+t) - t with t = (B/A)*u;  a = exp(Delta*A).
// ---------------------------------------------------------------------------
__global__ __launch_bounds__(256) void scan_p1_k(
    const ushort_t* __restrict__ Del_bf, const ushort_t* __restrict__ val_bf,
    const float* __restrict__ Bp, const float* __restrict__ A_log,
    float* __restrict__ aprod, float* __restrict__ hloc)
{
    int t = blockIdx.x * 256 + threadIdx.x;    // BB*NCH*DI = 131072
    int d = t & (DI - 1);
    int c = (t >> 10) & (NCH - 1);
    int b = t >> 16;

    float Adn[DS], ci[DS];
    const f4* alp = (const f4*)(A_log + (size_t)d * DS);
#pragma unroll
    for (int j = 0; j < 4; ++j) {
        f4 al = alp[j];
#pragma unroll
        for (int k = 0; k < 4; ++k) {
            float a = -__expf(al[k]);
            Adn[j * 4 + k] = a;
            ci[j * 4 + k] = 1.0f / a;
        }
    }
    int row0 = b * LL + c * CH;
    const ushort_t* Dp = Del_bf + (size_t)row0 * DI + d;
    const ushort_t* up = val_bf + (size_t)row0 * DI + d;
    const f4* bp = (const f4*)(Bp + (size_t)row0 * DS);

    float h[DS];
#pragma unroll
    for (int n = 0; n < DS; ++n) h[n] = 0.f;
    float sdv = 0.f;

#pragma unroll 2
    for (int l = 0; l < CH; ++l) {
        float dv = bf2f(Dp[(size_t)l * DI]);
        float u  = bf2f(up[(size_t)l * DI]);
        f4 q0 = bp[l * 4 + 0], q1 = bp[l * 4 + 1], q2 = bp[l * 4 + 2], q3 = bp[l * 4 + 3];
        float bn[DS];
#pragma unroll
        for (int k = 0; k < 4; ++k) {
            bn[k] = q0[k]; bn[4 + k] = q1[k]; bn[8 + k] = q2[k]; bn[12 + k] = q3[k];
        }
        sdv += dv;
#pragma unroll
        for (int n = 0; n < DS; ++n) {
            float a  = __expf(dv * Adn[n]);
            float tt = (ci[n] * bn[n]) * u;
            float s  = h[n] + tt;
            h[n] = fmaf(a, s, -tt);
        }
    }
    size_t o = (((size_t)b * NCH + c) * DI + d) * DS;
#pragma unroll
    for (int j = 0; j < 4; ++j) {
        f4 hv, av;
#pragma unroll
        for (int k = 0; k < 4; ++k) {
            hv[k] = h[j * 4 + k];
            av[k] = __expf(sdv * Adn[j * 4 + k]);
        }
        *(f4*)(hloc + o + j * 4) = hv;
        *(f4*)(aprod + o + j * 4) = av;
    }
}

__global__ __launch_bounds__(256) void scan_p2_k(
    const float* __restrict__ aprod, const float* __restrict__ hloc,
    float* __restrict__ hin)
{
    int t = blockIdx.x * 256 + threadIdx.x;    // BB*DI*DS = 32768
    int dn = t & (DI * DS - 1);
    int b = t >> 14;
    float h = 0.f;
    size_t base = (size_t)b * NCH * DI * DS + dn;
#pragma unroll 4
    for (int c = 0; c < NCH; ++c) {
        size_t idx = base + (size_t)c * (DI * DS);
        hin[idx] = h;
        h = fmaf(aprod[idx], h, hloc[idx]);
    }
}

// phase 3: recompute with correct h_in; fused gate: g_bf = bf16(y * silu(zgate))
__global__ __launch_bounds__(256) void scan_p3_k(
    const ushort_t* __restrict__ Del_bf, const ushort_t* __restrict__ val_bf,
    const float* __restrict__ Bp, const float* __restrict__ Cp,
    const float* __restrict__ A_log, const float* __restrict__ hin,
    const ushort_t* __restrict__ z_bf, ushort_t* __restrict__ g_bf)
{
    int t = blockIdx.x * 256 + threadIdx.x;    // BB*NCH*DI
    int d = t & (DI - 1);
    int c = (t >> 10) & (NCH - 1);
    int b = t >> 16;

    float Adn[DS], ci[DS];
    const f4* alp = (const f4*)(A_log + (size_t)d * DS);
#pragma unroll
    for (int j = 0; j < 4; ++j) {
        f4 al = alp[j];
#pragma unroll
        for (int k = 0; k < 4; ++k) {
            float a = -__expf(al[k]);
            Adn[j * 4 + k] = a;
            ci[j * 4 + k] = 1.0f / a;
        }
    }
    int row0 = b * LL + c * CH;
    const ushort_t* Dp = Del_bf + (size_t)row0 * DI + d;
    const ushort_t* up = val_bf + (size_t)row0 * DI + d;
    const ushort_t* zp = z_bf + (size_t)row0 * (2 * DI) + DI + d;
    const f4* bp = (const f4*)(Bp + (size_t)row0 * DS);
    const f4* cp = (const f4*)(Cp + (size_t)row0 * DS);
    ushort_t* gp = g_bf + (size_t)row0 * DI + d;

    float h[DS];
    size_t o = (((size_t)b * NCH + c) * DI + d) * DS;
#pragma unroll
    for (int j = 0; j < 4; ++j) {
        f4 hv = *(const f4*)(hin + o + j * 4);
#pragma unroll
        for (int k = 0; k < 4; ++k) h[j * 4 + k] = hv[k];
    }

#pragma unroll 2
    for (int l = 0; l < CH; ++l) {
        float dv = bf2f(Dp[(size_t)l * DI]);
        float u  = bf2f(up[(size_t)l * DI]);
        f4 q0 = bp[l * 4 + 0], q1 = bp[l * 4 + 1], q2 = bp[l * 4 + 2], q3 = bp[l * 4 + 3];
        f4 r0 = cp[l * 4 + 0], r1 = cp[l * 4 + 1], r2 = cp[l * 4 + 2], r3 = cp[l * 4 + 3];
        float bn[DS], cn[DS];
#pragma unroll
        for (int k = 0; k < 4; ++k) {
            bn[k] = q0[k]; bn[4 + k] = q1[k]; bn[8 + k] = q2[k]; bn[12 + k] = q3[k];
            cn[k] = r0[k]; cn[4 + k] = r1[k]; cn[8 + k] = r2[k]; cn[12 + k] = r3[k];
        }
        float psum = 0.f;
#pragma unroll
        for (int n = 0; n < DS; ++n) {
            float a  = __expf(dv * Adn[n]);
            float tt = (ci[n] * bn[n]) * u;
            float s  = h[n] + tt;
            h[n] = fmaf(a, s, -tt);
            psum = fmaf(h[n], cn[n], psum);
        }
        float zg = bf2f(zp[(size_t)l * 2 * DI]);
        float si = zg / (1.f + __expf(-zg));
        gp[(size_t)l * DI] = f2bf(psum * si);
    }
}

// ---------------------------------------------------------------------------
extern "C" void kernel_launch(void* const* d_in, const int* in_sizes, int n_in,
                              void* d_out, int out_size, void* d_ws, size_t ws_size,
                              hipStream_t stream)
{
    (void)in_sizes; (void)n_in; (void)out_size; (void)ws_size;

    const float* x        = (const float*)d_in[0];
    const float* W_in     = (const float*)d_in[1];
    const float* conv_w   = (const float*)d_in[2];
    const float* W_B      = (const float*)d_in[3];
    const float* W_C      = (const float*)d_in[4];
    const float* W_delta  = (const float*)d_in[5];
    const float* delta_b  = (const float*)d_in[6];
    const float* W_tau    = (const float*)d_in[7];
    const float* A_log    = (const float*)d_in[8];
    const float* W_out    = (const float*)d_in[9];
    float* out = (float*)d_out;

    const size_t M1 = 1024 * 1024;
    ushort_t* us = (ushort_t*)d_ws;
    ushort_t* z_bf   = us;                    // 4M ushort
    ushort_t* val_bf = us + 4 * M1;           // 2M
    ushort_t* Del_bf = us + 6 * M1;           // 2M
    ushort_t* x_bf   = us + 8 * M1;           // 2M
    ushort_t* g_bf   = us + 10 * M1;          // 2M
    ushort_t* WinT   = us + 12 * M1;          // 2M
    ushort_t* WoT    = us + 14 * M1;          // 1M
    ushort_t* WtT    = us + 15 * M1;          // 1M
    ushort_t* Wd_bf  = us + 16 * M1;          // 1M
    ushort_t* WdcT   = us + 17 * M1;          // NP*1024 = 1.0625M (~36.1MB end)
    float* fb    = (float*)(us + 20 * M1);    // 40MB offset
    float* Bp    = fb;                         // 32768
    float* Cp    = fb + (size_t)ROWS * DS;     // 32768
    float* bias2 = fb + 2 * (size_t)ROWS * DS; // 1024
    float* aprod = bias2 + 1024;               // 2M fl
    float* hloc  = aprod + 2 * M1;             // 2M fl
    float* hin   = hloc + 2 * M1;              // 2M fl (~64.3MB end)

    // 0) converts / weight prep
    cvt_bf_k<<<(ROWS * DM / 4) / 256, 256, 0, stream>>>(x, x_bf);
    cvt_bf_k<<<(DI * DM / 4) / 256, 256, 0, stream>>>(W_delta, Wd_bf);
    tconv_k<<<dim3(2 * DI / 32, DM / 32), 256, 0, stream>>>(W_in, WinT, DM, 2 * DI);
    tconv_k<<<dim3(DM / 32, DM / 32), 256, 0, stream>>>(W_tau, WtT, DM, DM);
    tconv_k<<<dim3(DM / 32, DI / 32), 256, 0, stream>>>(W_out, WoT, DI, DM);
    tail_pack_k<<<(64 * DM) / 256, 256, 0, stream>>>(W_B, W_C, WdcT);
    bias2_k<<<DM / 4, 256, 0, stream>>>(delta_b, WtT, bias2);

    // 0b) fused weight: WdcT[n][i] = (W_delta @ W_tau)^T = W_tau^T @ W_delta^T
    gemm_bf_k<64, 0, false, false, true, false><<<dim3(DM / 64, DI / 128), 256, 0, stream>>>(
        WtT, Wd_bf, nullptr, nullptr, WdcT, nullptr, nullptr, DM, DI, DM, DM);

    // 1) z = x @ W_in  (bf16 out)
    gemm_bf_k<128, 0, false, false, true, false><<<dim3(2 * DI / 128, ROWS / 128), 256, 0, stream>>>(
        x_bf, WinT, nullptr, nullptr, z_bf, nullptr, nullptr, ROWS, 2 * DI, DM, 2 * DI);

    // 2) val = silu(conv1d(z[:, :DI]))
    conv_silu_k<<<(ROWS * DI / 4) / 256, 256, 0, stream>>>(z_bf, conv_w, val_bf);

    // 3) Delta = softplus(val @ Wfused + bias2) -> Del_bf; fused B/C proj -> Bp,Cp
    gemm_bf_k<64, 1, true, false, true, true><<<dim3(NP / 64, ROWS / 128), 256, 0, stream>>>(
        val_bf, WdcT, bias2, nullptr, Del_bf, Bp, Cp, ROWS, NP, DI, DM);

    // 4) chunked selective scan; p3 fuses gate -> g_bf
    scan_p1_k<<<(BB * NCH * DI) / 256, 256, 0, stream>>>(
        Del_bf, val_bf, Bp, A_log, aprod, hloc);
    scan_p2_k<<<(BB * DI * DS) / 256, 256, 0, stream>>>(aprod, hloc, hin);
    scan_p3_k<<<(BB * NCH * DI) / 256, 256, 0, stream>>>(
        Del_bf, val_bf, Bp, Cp, A_log, hin, z_bf, g_bf);

    // 5) out = g @ W_out + x (fp32 out)
    gemm_bf_k<64, 0, false, true, false, false><<<dim3(DM / 64, ROWS / 128), 256, 0, stream>>>(
        g_bf, WoT, nullptr, x, out, nullptr, nullptr, ROWS, DM, DI, DM);
}

// Round 8
// 244.686 us; speedup vs baseline: 1.3882x; 1.0420x over previous
//
#include <hip/hip_runtime.h>
#include <math.h>

// Problem constants (MambaBlock reference)
#define BB 2
#define LL 1024
#define DM 1024
#define DI 1024
#define DS 16
#define ROWS (BB * LL)   // 2048
#define CH 16            // scan chunk length
#define NCH (LL / CH)    // 64 chunks
#define NP 1088          // main GEMM N: 1024 Delta + 16 B + 16 C + 32 zero pad
#define NF 1088          // fuse GEMM N: 1024 W_delta rows + 1 delta_base + 63 pad

typedef unsigned short ushort_t;
typedef __attribute__((ext_vector_type(8))) short short8;
typedef __attribute__((ext_vector_type(4))) float f32x4;
typedef __attribute__((ext_vector_type(4))) float f4;
typedef __attribute__((ext_vector_type(4))) ushort_t us4;

static __device__ __forceinline__ float sp_f(float x) {
    return fmaxf(x, 0.f) + log1pf(expf(-fabsf(x)));
}
static __device__ __forceinline__ ushort_t f2bf(float f) {
    unsigned u = __float_as_uint(f);
    u += 0x7fffu + ((u >> 16) & 1u);
    return (ushort_t)(u >> 16);
}
static __device__ __forceinline__ float bf2f(ushort_t s) {
    return __uint_as_float(((unsigned)s) << 16);
}

// LDS XOR swizzle (involution: flips addr bits 4,5 keyed by bits 7,8).
#define SWZ(L) ((L) ^ ((((L) >> 7) & 1) << 4) ^ ((((L) >> 8) & 1) << 5))

static __device__ __forceinline__ void gl_lds16(const void* g, void* l) {
    __builtin_amdgcn_global_load_lds(
        (const __attribute__((address_space(1))) unsigned int*)g,
        (__attribute__((address_space(3))) unsigned int*)l, 16, 0, 0);
}

// ---------------------------------------------------------------------------
// bf16 MFMA GEMM: C[M,N] = epi(A[M,K] @ Bt[N,K]^T), output stride ldc.
// 128xTN tile (TN=128 or 64), BK=32, 256 threads (4 waves 2x2).
// global_load_lds staging (pre-swizzled source), LDS double buffer,
// one barrier per K-step; XCD-aware block swizzle (grid count % 8 == 0).
// PROJMODE 0: plain epilogue.  1: cols>=DM -> Bp/Cp (fp32).  2: col==DM -> b2.
// ---------------------------------------------------------------------------
template <int TN, int ACT, bool HAS_BIAS, bool HAS_RES, bool OUTBF, int PROJMODE>
__global__ __launch_bounds__(256) void gemm_bf_k(
    const ushort_t* __restrict__ A, const ushort_t* __restrict__ Bt,
    const float* __restrict__ bias, const float* __restrict__ res,
    void* __restrict__ Cout, float* __restrict__ BpO, float* __restrict__ CpO,
    int M, int N, int K, int ldc)
{
    constexpr int NACC = TN / 32;     // N-frags per wave
    constexpr int BCH = TN / 64;      // 1KB B-staging chunks per wave
    __shared__ __align__(16) char lsa[2][8192];      // A tile [128][32] bf16
    __shared__ __align__(16) char lsb[2][TN * 64];   // B tile [TN][32] bf16

    const int tid = threadIdx.x;
    const int lane = tid & 63;
    const int w = tid >> 6;
    const int wr = w >> 1, wc = w & 1;

    // XCD-aware bijective swizzle (T1): all launches have nwg % 8 == 0, so
    // each XCD gets a contiguous chunk of tiles -> B panels L2-resident.
    int wg = blockIdx.y * gridDim.x + blockIdx.x;
    const int nwg = gridDim.x * gridDim.y;
    wg = (wg & 7) * (nwg >> 3) + (wg >> 3);
    const int bx = wg % gridDim.x, by = wg / gridDim.x;
    const int row0 = by * 128, col0 = bx * TN;

    const int rl = lane & 15, q = lane >> 4;

    // per-lane pre-swizzled global sources (bytes); LDS dest is linear.
    const char* gA[2];
#pragma unroll
    for (int j = 0; j < 2; ++j) {
        int Lc = (w * 2 + j) * 1024 + lane * 16;
        int L = SWZ(Lc);
        gA[j] = (const char*)A + ((size_t)(row0 + (L >> 6)) * K) * 2 + (L & 63);
    }
    const char* gB[BCH];
#pragma unroll
    for (int j = 0; j < BCH; ++j) {
        int Lc = (w * BCH + j) * 1024 + lane * 16;
        int L = SWZ(Lc);
        gB[j] = (const char*)Bt + ((size_t)(col0 + (L >> 6)) * K) * 2 + (L & 63);
    }

    int LA[4], LB[NACC];
#pragma unroll
    for (int m = 0; m < 4; ++m) LA[m] = SWZ((wr * 64 + m * 16 + rl) * 64 + q * 16);
#pragma unroll
    for (int n = 0; n < NACC; ++n)
        LB[n] = SWZ((wc * (TN / 2) + n * 16 + rl) * 64 + q * 16);

    f32x4 acc[4][NACC] = {};
    const int NT = K >> 5;

    // prologue: stage K-tile 0 into buf 0
#pragma unroll
    for (int j = 0; j < 2; ++j) gl_lds16(gA[j], &lsa[0][(w * 2 + j) * 1024]);
#pragma unroll
    for (int j = 0; j < BCH; ++j) gl_lds16(gB[j], &lsb[0][(w * BCH + j) * 1024]);
    __syncthreads();   // drains vmcnt(0): tile 0 resident

    int cur = 0;
    for (int kt = 0; kt < NT; ++kt) {
        if (kt + 1 < NT) {   // async issue of next tile; hides under MFMA
            const int kb = (kt + 1) * 64;
#pragma unroll
            for (int j = 0; j < 2; ++j)
                gl_lds16(gA[j] + kb, &lsa[cur ^ 1][(w * 2 + j) * 1024]);
#pragma unroll
            for (int j = 0; j < BCH; ++j)
                gl_lds16(gB[j] + kb, &lsb[cur ^ 1][(w * BCH + j) * 1024]);
        }
        short8 af[4], bfr[NACC];
#pragma unroll
        for (int m = 0; m < 4; ++m) af[m] = *(const short8*)(&lsa[cur][LA[m]]);
#pragma unroll
        for (int n = 0; n < NACC; ++n) bfr[n] = *(const short8*)(&lsb[cur][LB[n]]);
#pragma unroll
        for (int m = 0; m < 4; ++m)
#pragma unroll
            for (int n = 0; n < NACC; ++n)
                acc[m][n] = __builtin_amdgcn_mfma_f32_16x16x32_bf16(
                    af[m], bfr[n], acc[m][n], 0, 0, 0);
        __syncthreads();   // all reads of buf[cur] done; next tile resident
        cur ^= 1;
    }

    float bia[NACC];
#pragma unroll
    for (int n = 0; n < NACC; ++n) {
        int c = col0 + wc * (TN / 2) + n * 16 + rl;
        bia[n] = (HAS_BIAS && c < DM) ? bias[c] : 0.f;
    }
#pragma unroll
    for (int m = 0; m < 4; ++m) {
#pragma unroll
        for (int n = 0; n < NACC; ++n) {
            int c = col0 + wc * (TN / 2) + n * 16 + rl;
#pragma unroll
            for (int i = 0; i < 4; ++i) {
                int r = row0 + wr * 64 + m * 16 + q * 4 + i;
                float v = acc[m][n][i];
                if (PROJMODE == 1 && c >= DM) {
                    if (c < DM + DS)          BpO[(size_t)r * DS + (c - DM)] = v;
                    else if (c < DM + 2 * DS) CpO[(size_t)r * DS + (c - DM - DS)] = v;
                } else if (PROJMODE == 2 && c >= DM) {
                    if (c == DM) BpO[r] = v;
                } else {
                    v += bia[n];
                    if (ACT == 1) v = sp_f(v);
                    if (HAS_RES) v += res[(size_t)r * ldc + c];
                    if (OUTBF) ((ushort_t*)Cout)[(size_t)r * ldc + c] = f2bf(v);
                    else       ((float*)Cout)[(size_t)r * ldc + c] = v;
                }
            }
        }
    }
}

// ---------------------------------------------------------------------------
// Merged prep kernel (region-branched on blockIdx.x; all regions read only
// kernel inputs -> no intra-kernel dependencies).
//  [0,2048)     x fp32 -> x_bf (4/thread)
//  [2048,3072)  W_delta fp32 -> WdX rows [0,1024)
//  [3072,3328)  WdX rows [1024,1088): row 1024 = bf16(delta_base), rest 0
//  [3328,5376)  W_in  [1024][2048] -> WinT [2048][1024] (transpose-cvt)
//  [5376,6400)  W_tau [1024][1024] -> WtT
//  [6400,7424)  W_out [1024][1024] -> WoT
//  [7424,7680)  WdcT rows [1024,1088): W_B^T(16), W_C^T(16), zeros(32)
// ---------------------------------------------------------------------------
static __device__ __forceinline__ void tconv_body(
    const float* __restrict__ in, ushort_t* __restrict__ out,
    int K, int N, int n0, int k0, float (*t)[33], int tid)
{
    int lx = tid & 31, ly = tid >> 5;
#pragma unroll
    for (int i = 0; i < 32; i += 8)
        t[ly + i][lx] = in[(size_t)(k0 + ly + i) * N + n0 + lx];
    __syncthreads();
#pragma unroll
    for (int i = 0; i < 32; i += 8)
        out[(size_t)(n0 + ly + i) * K + k0 + lx] = f2bf(t[lx][ly + i]);
}

__global__ __launch_bounds__(256) void prep_k(
    const float* __restrict__ x, const float* __restrict__ W_in,
    const float* __restrict__ W_B, const float* __restrict__ W_C,
    const float* __restrict__ W_delta, const float* __restrict__ db,
    const float* __restrict__ W_tau, const float* __restrict__ W_out,
    ushort_t* __restrict__ x_bf, ushort_t* __restrict__ WinT,
    ushort_t* __restrict__ WtT, ushort_t* __restrict__ WoT,
    ushort_t* __restrict__ WdX, ushort_t* __restrict__ WdcT)
{
    __shared__ float t[32][33];
    const int blk = blockIdx.x;
    const int tid = threadIdx.x;
    if (blk < 2048) {
        int i = blk * 256 + tid;
        f4 v = ((const f4*)x)[i];
        us4 o; o.x = f2bf(v.x); o.y = f2bf(v.y); o.z = f2bf(v.z); o.w = f2bf(v.w);
        ((us4*)x_bf)[i] = o;
    } else if (blk < 3072) {
        int i = (blk - 2048) * 256 + tid;
        f4 v = ((const f4*)W_delta)[i];
        us4 o; o.x = f2bf(v.x); o.y = f2bf(v.y); o.z = f2bf(v.z); o.w = f2bf(v.w);
        ((us4*)WdX)[i] = o;
    } else if (blk < 3328) {
        int i = (blk - 3072) * 256 + tid;       // 0..65535
        int k = i & 1023, r = i >> 10;          // r 0..63
        WdX[(size_t)(1024 + r) * 1024 + k] = (r == 0) ? f2bf(db[k]) : (ushort_t)0;
    } else if (blk < 5376) {
        int tau = blk - 3328;
        tconv_body(W_in, WinT, 1024, 2048, (tau & 63) * 32, (tau >> 6) * 32, t, tid);
    } else if (blk < 6400) {
        int tau = blk - 5376;
        tconv_body(W_tau, WtT, 1024, 1024, (tau & 31) * 32, (tau >> 5) * 32, t, tid);
    } else if (blk < 7424) {
        int tau = blk - 6400;
        tconv_body(W_out, WoT, 1024, 1024, (tau & 31) * 32, (tau >> 5) * 32, t, tid);
    } else {
        int i = (blk - 7424) * 256 + tid;       // 0..65535
        int k = i & 1023, r = i >> 10;          // r 0..63
        ushort_t v = 0;
        if (r < DS)          v = f2bf(W_B[(size_t)k * DS + r]);
        else if (r < 2 * DS) v = f2bf(W_C[(size_t)k * DS + (r - DS)]);
        WdcT[(size_t)(1024 + r) * 1024 + k] = v;
    }
}

// ---------------------------------------------------------------------------
// Depthwise conv1d (K=3, same padding) + SiLU.  bf16 in (z), bf16 out (val).
// ---------------------------------------------------------------------------
__global__ __launch_bounds__(256) void conv_silu_k(
    const ushort_t* __restrict__ z_bf, const float* __restrict__ cw,
    ushort_t* __restrict__ val_bf)
{
    int t = blockIdx.x * 256 + threadIdx.x;    // ROWS*DI/4
    int c0 = (t & 255) * 4;
    int row = t >> 8;
    int l = row & (LL - 1);
    const ushort_t* zr = z_bf + (size_t)row * (2 * DI) + c0;
    us4 zz = {0, 0, 0, 0};
    us4 vm = (l > 0)      ? *(const us4*)(zr - 2 * DI) : zz;
    us4 v0 = *(const us4*)(zr);
    us4 vp = (l < LL - 1) ? *(const us4*)(zr + 2 * DI) : zz;
    const f4* wp = (const f4*)(cw + (size_t)c0 * 3);
    f4 w0 = wp[0], w1 = wp[1], w2 = wp[2];
    float w[12];
#pragma unroll
    for (int k = 0; k < 4; ++k) { w[k] = w0[k]; w[4 + k] = w1[k]; w[8 + k] = w2[k]; }
    us4 o;
#pragma unroll
    for (int j = 0; j < 4; ++j) {
        float s = bf2f(vm[j]) * w[3 * j] + bf2f(v0[j]) * w[3 * j + 1]
                + bf2f(vp[j]) * w[3 * j + 2];
        float si = s / (1.f + __expf(-s));
        o[j] = f2bf(si);
    }
    *(us4*)(val_bf + (size_t)row * DI + c0) = o;
}

// ---------------------------------------------------------------------------
// Chunked selective scan, thread per (b,d,chunk), 16 n in registers.
// h = a*(h+t) - t with t = (B/A)*u;  a = exp(Delta*A).
// ---------------------------------------------------------------------------
__global__ __launch_bounds__(256) void scan_p1_k(
    const ushort_t* __restrict__ Del_bf, const ushort_t* __restrict__ val_bf,
    const float* __restrict__ Bp, const float* __restrict__ A_log,
    float* __restrict__ aprod, float* __restrict__ hloc)
{
    int t = blockIdx.x * 256 + threadIdx.x;    // BB*NCH*DI = 131072
    int d = t & (DI - 1);
    int c = (t >> 10) & (NCH - 1);
    int b = t >> 16;

    float Adn[DS], ci[DS];
    const f4* alp = (const f4*)(A_log + (size_t)d * DS);
#pragma unroll
    for (int j = 0; j < 4; ++j) {
        f4 al = alp[j];
#pragma unroll
        for (int k = 0; k < 4; ++k) {
            float a = -__expf(al[k]);
            Adn[j * 4 + k] = a;
            ci[j * 4 + k] = 1.0f / a;
        }
    }
    int row0 = b * LL + c * CH;
    const ushort_t* Dp = Del_bf + (size_t)row0 * DI + d;
    const ushort_t* up = val_bf + (size_t)row0 * DI + d;
    const f4* bp = (const f4*)(Bp + (size_t)row0 * DS);

    float h[DS];
#pragma unroll
    for (int n = 0; n < DS; ++n) h[n] = 0.f;
    float sdv = 0.f;

#pragma unroll 2
    for (int l = 0; l < CH; ++l) {
        float dv = bf2f(Dp[(size_t)l * DI]);
        float u  = bf2f(up[(size_t)l * DI]);
        f4 q0 = bp[l * 4 + 0], q1 = bp[l * 4 + 1], q2 = bp[l * 4 + 2], q3 = bp[l * 4 + 3];
        float bn[DS];
#pragma unroll
        for (int k = 0; k < 4; ++k) {
            bn[k] = q0[k]; bn[4 + k] = q1[k]; bn[8 + k] = q2[k]; bn[12 + k] = q3[k];
        }
        sdv += dv;
#pragma unroll
        for (int n = 0; n < DS; ++n) {
            float a  = __expf(dv * Adn[n]);
            float tt = (ci[n] * bn[n]) * u;
            float s  = h[n] + tt;
            h[n] = fmaf(a, s, -tt);
        }
    }
    size_t o = (((size_t)b * NCH + c) * DI + d) * DS;
#pragma unroll
    for (int j = 0; j < 4; ++j) {
        f4 hv, av;
#pragma unroll
        for (int k = 0; k < 4; ++k) {
            hv[k] = h[j * 4 + k];
            av[k] = __expf(sdv * Adn[j * 4 + k]);
        }
        *(f4*)(hloc + o + j * 4) = hv;
        *(f4*)(aprod + o + j * 4) = av;
    }
}

__global__ __launch_bounds__(256) void scan_p2_k(
    const float* __restrict__ aprod, const float* __restrict__ hloc,
    float* __restrict__ hin)
{
    int t = blockIdx.x * 256 + threadIdx.x;    // BB*DI*DS = 32768
    int dn = t & (DI * DS - 1);
    int b = t >> 14;
    float h = 0.f;
    size_t base = (size_t)b * NCH * DI * DS + dn;
#pragma unroll 4
    for (int c = 0; c < NCH; ++c) {
        size_t idx = base + (size_t)c * (DI * DS);
        hin[idx] = h;
        h = fmaf(aprod[idx], h, hloc[idx]);
    }
}

// phase 3: recompute with correct h_in; fused gate: g_bf = bf16(y * silu(zgate))
__global__ __launch_bounds__(256) void scan_p3_k(
    const ushort_t* __restrict__ Del_bf, const ushort_t* __restrict__ val_bf,
    const float* __restrict__ Bp, const float* __restrict__ Cp,
    const float* __restrict__ A_log, const float* __restrict__ hin,
    const ushort_t* __restrict__ z_bf, ushort_t* __restrict__ g_bf)
{
    int t = blockIdx.x * 256 + threadIdx.x;    // BB*NCH*DI
    int d = t & (DI - 1);
    int c = (t >> 10) & (NCH - 1);
    int b = t >> 16;

    float Adn[DS], ci[DS];
    const f4* alp = (const f4*)(A_log + (size_t)d * DS);
#pragma unroll
    for (int j = 0; j < 4; ++j) {
        f4 al = alp[j];
#pragma unroll
        for (int k = 0; k < 4; ++k) {
            float a = -__expf(al[k]);
            Adn[j * 4 + k] = a;
            ci[j * 4 + k] = 1.0f / a;
        }
    }
    int row0 = b * LL + c * CH;
    const ushort_t* Dp = Del_bf + (size_t)row0 * DI + d;
    const ushort_t* up = val_bf + (size_t)row0 * DI + d;
    const ushort_t* zp = z_bf + (size_t)row0 * (2 * DI) + DI + d;
    const f4* bp = (const f4*)(Bp + (size_t)row0 * DS);
    const f4* cp = (const f4*)(Cp + (size_t)row0 * DS);
    ushort_t* gp = g_bf + (size_t)row0 * DI + d;

    float h[DS];
    size_t o = (((size_t)b * NCH + c) * DI + d) * DS;
#pragma unroll
    for (int j = 0; j < 4; ++j) {
        f4 hv = *(const f4*)(hin + o + j * 4);
#pragma unroll
        for (int k = 0; k < 4; ++k) h[j * 4 + k] = hv[k];
    }

#pragma unroll 2
    for (int l = 0; l < CH; ++l) {
        float dv = bf2f(Dp[(size_t)l * DI]);
        float u  = bf2f(up[(size_t)l * DI]);
        f4 q0 = bp[l * 4 + 0], q1 = bp[l * 4 + 1], q2 = bp[l * 4 + 2], q3 = bp[l * 4 + 3];
        f4 r0 = cp[l * 4 + 0], r1 = cp[l * 4 + 1], r2 = cp[l * 4 + 2], r3 = cp[l * 4 + 3];
        float bn[DS], cn[DS];
#pragma unroll
        for (int k = 0; k < 4; ++k) {
            bn[k] = q0[k]; bn[4 + k] = q1[k]; bn[8 + k] = q2[k]; bn[12 + k] = q3[k];
            cn[k] = r0[k]; cn[4 + k] = r1[k]; cn[8 + k] = r2[k]; cn[12 + k] = r3[k];
        }
        float psum = 0.f;
#pragma unroll
        for (int n = 0; n < DS; ++n) {
            float a  = __expf(dv * Adn[n]);
            float tt = (ci[n] * bn[n]) * u;
            float s  = h[n] + tt;
            h[n] = fmaf(a, s, -tt);
            psum = fmaf(h[n], cn[n], psum);
        }
        float zg = bf2f(zp[(size_t)l * 2 * DI]);
        float si = zg / (1.f + __expf(-zg));
        gp[(size_t)l * DI] = f2bf(psum * si);
    }
}

// ---------------------------------------------------------------------------
extern "C" void kernel_launch(void* const* d_in, const int* in_sizes, int n_in,
                              void* d_out, int out_size, void* d_ws, size_t ws_size,
                              hipStream_t stream)
{
    (void)in_sizes; (void)n_in; (void)out_size; (void)ws_size;

    const float* x        = (const float*)d_in[0];
    const float* W_in     = (const float*)d_in[1];
    const float* conv_w   = (const float*)d_in[2];
    const float* W_B      = (const float*)d_in[3];
    const float* W_C      = (const float*)d_in[4];
    const float* W_delta  = (const float*)d_in[5];
    const float* delta_b  = (const float*)d_in[6];
    const float* W_tau    = (const float*)d_in[7];
    const float* A_log    = (const float*)d_in[8];
    const float* W_out    = (const float*)d_in[9];
    float* out = (float*)d_out;

    const size_t M1 = 1024 * 1024;
    ushort_t* us = (ushort_t*)d_ws;
    ushort_t* z_bf   = us;                    // 4M ushort
    ushort_t* val_bf = us + 4 * M1;           // 2M
    ushort_t* Del_bf = us + 6 * M1;           // 2M
    ushort_t* x_bf   = us + 8 * M1;           // 2M
    ushort_t* g_bf   = us + 10 * M1;          // 2M
    ushort_t* WinT   = us + 12 * M1;          // 2M
    ushort_t* WoT    = us + 14 * M1;          // 1M
    ushort_t* WtT    = us + 15 * M1;          // 1M
    ushort_t* WdX    = us + 16 * M1;          // NF*1024 = 1,114,112
    ushort_t* WdcT   = WdX + (size_t)NF * 1024;   // NP*1024 (~36.5MB end)
    float* fb    = (float*)(us + 20 * M1);    // 40MB offset
    float* Bp    = fb;                         // 32768
    float* Cp    = fb + (size_t)ROWS * DS;     // 32768
    float* b2    = fb + 2 * (size_t)ROWS * DS; // 1024
    float* aprod = b2 + 1024;                  // 2M fl
    float* hloc  = aprod + 2 * M1;             // 2M fl
    float* hin   = hloc + 2 * M1;              // 2M fl (~64.3MB end)

    // 0) merged prep: converts, transposes, tail rows
    prep_k<<<7680, 256, 0, stream>>>(x, W_in, W_B, W_C, W_delta, delta_b,
                                     W_tau, W_out, x_bf, WinT, WtT, WoT, WdX, WdcT);

    // 0b) fused weight: WdcT[n][i] = sum_m WtT[n][m]*W_delta[i][m]; col 1024 -> b2
    gemm_bf_k<64, 0, false, false, true, 2><<<dim3(NF / 64, DM / 128), 256, 0, stream>>>(
        WtT, WdX, nullptr, nullptr, WdcT, b2, nullptr, DM, NF, DM, DM);

    // 1) z = x @ W_in  (bf16 out)
    gemm_bf_k<128, 0, false, false, true, 0><<<dim3(2 * DI / 128, ROWS / 128), 256, 0, stream>>>(
        x_bf, WinT, nullptr, nullptr, z_bf, nullptr, nullptr, ROWS, 2 * DI, DM, 2 * DI);

    // 2) val = silu(conv1d(z[:, :DI]))
    conv_silu_k<<<(ROWS * DI / 4) / 256, 256, 0, stream>>>(z_bf, conv_w, val_bf);

    // 3) Delta = softplus(val @ Wfused + b2) -> Del_bf; fused B/C proj -> Bp,Cp
    gemm_bf_k<64, 1, true, false, true, 1><<<dim3(NP / 64, ROWS / 128), 256, 0, stream>>>(
        val_bf, WdcT, b2, nullptr, Del_bf, Bp, Cp, ROWS, NP, DI, DM);

    // 4) chunked selective scan; p3 fuses gate -> g_bf
    scan_p1_k<<<(BB * NCH * DI) / 256, 256, 0, stream>>>(
        Del_bf, val_bf, Bp, A_log, aprod, hloc);
    scan_p2_k<<<(BB * DI * DS) / 256, 256, 0, stream>>>(aprod, hloc, hin);
    scan_p3_k<<<(BB * NCH * DI) / 256, 256, 0, stream>>>(
        Del_bf, val_bf, Bp, Cp, A_log, hin, z_bf, g_bf);

    // 5) out = g @ W_out + x (fp32 out)
    gemm_bf_k<64, 0, false, true, false, 0><<<dim3(DM / 64, ROWS / 128), 256, 0, stream>>>(
        g_bf, WoT, nullptr, x, out, nullptr, nullptr, ROWS, DM, DI, DM);
}

// Round 9
// 239.859 us; speedup vs baseline: 1.4161x; 1.0201x over previous
//
#include <hip/hip_runtime.h>
#include <math.h>

// Problem constants (MambaBlock reference)
#define BB 2
#define LL 1024
#define DM 1024
#define DI 1024
#define DS 16
#define ROWS (BB * LL)   // 2048
#define CH 16            // scan chunk length
#define NCH (LL / CH)    // 64 chunks
#define NP 1152          // main GEMM N: 1024 Delta + 16 B + 16 C + 96 zero pad
#define NF 1152          // fuse GEMM N: 1024 W_delta rows + 1 delta_base + 127 pad

typedef unsigned short ushort_t;
typedef __attribute__((ext_vector_type(8))) short short8;
typedef __attribute__((ext_vector_type(4))) float f32x4;
typedef __attribute__((ext_vector_type(4))) float f4;
typedef __attribute__((ext_vector_type(4))) ushort_t us4;

static __device__ __forceinline__ float sp_f(float x) {
    return fmaxf(x, 0.f) + log1pf(expf(-fabsf(x)));
}
static __device__ __forceinline__ ushort_t f2bf(float f) {
    unsigned u = __float_as_uint(f);
    u += 0x7fffu + ((u >> 16) & 1u);
    return (ushort_t)(u >> 16);
}
static __device__ __forceinline__ float bf2f(ushort_t s) {
    return __uint_as_float(((unsigned)s) << 16);
}

// LDS XOR swizzle (involution: flips addr bits 4,5 keyed by bits 7,8).
// Applied to BOTH the global source of global_load_lds (linear LDS dest)
// and the ds_read fragment addresses (both-sides rule, §5.5 T21 / m173).
#define SWZ(L) ((L) ^ ((((L) >> 7) & 1) << 4) ^ ((((L) >> 8) & 1) << 5))

static __device__ __forceinline__ void gl_lds16(const void* g, void* l) {
    __builtin_amdgcn_global_load_lds(
        (const __attribute__((address_space(1))) unsigned int*)g,
        (__attribute__((address_space(3))) unsigned int*)l, 16, 0, 0);
}

// ---------------------------------------------------------------------------
// bf16 MFMA GEMM: C[M,N] = epi(A[M,K] @ Bt[N,K]^T), output stride ldc.
// 64x128 tile, BK=32, 256 threads (4 waves 2x2, each 32x64 -> acc[2][4]).
// Tile halved (vs 128x128) so grids are >=2 blocks/CU: inter-block wave
// overlap (m114) hides the per-iter vmcnt(0)+barrier drain that 1-block/CU
// grids fully expose.  global_load_lds staging, LDS dbuf, 2-phase loop,
// XCD-aware block swizzle (all grids % 8 == 0).
// PROJMODE 0: plain epilogue.  1: cols>=DM -> Bp/Cp (fp32).  2: col==DM -> b2.
// ---------------------------------------------------------------------------
template <int ACT, bool HAS_BIAS, bool HAS_RES, bool OUTBF, int PROJMODE>
__global__ __launch_bounds__(256) void gemm_bf_k(
    const ushort_t* __restrict__ A, const ushort_t* __restrict__ Bt,
    const float* __restrict__ bias, const float* __restrict__ res,
    void* __restrict__ Cout, float* __restrict__ BpO, float* __restrict__ CpO,
    int M, int N, int K, int ldc)
{
    __shared__ __align__(16) char lsa[2][4096];   // A tile [64][32] bf16
    __shared__ __align__(16) char lsb[2][8192];   // B tile [128][32] bf16

    const int tid = threadIdx.x;
    const int lane = tid & 63;
    const int w = tid >> 6;
    const int wr = w >> 1, wc = w & 1;

    // XCD-aware bijective swizzle (T1): all launches have nwg % 8 == 0.
    int wg = blockIdx.y * gridDim.x + blockIdx.x;
    const int nwg = gridDim.x * gridDim.y;
    wg = (wg & 7) * (nwg >> 3) + (wg >> 3);
    const int bx = wg % gridDim.x, by = wg / gridDim.x;
    const int row0 = by * 64, col0 = bx * 128;

    const int rl = lane & 15, q = lane >> 4;

    // per-lane pre-swizzled global sources (bytes); LDS dest is linear.
    const char* gA;
    {
        int L = SWZ(w * 1024 + lane * 16);
        gA = (const char*)A + ((size_t)(row0 + (L >> 6)) * K) * 2 + (L & 63);
    }
    const char* gB[2];
#pragma unroll
    for (int j = 0; j < 2; ++j) {
        int L = SWZ((w * 2 + j) * 1024 + lane * 16);
        gB[j] = (const char*)Bt + ((size_t)(col0 + (L >> 6)) * K) * 2 + (L & 63);
    }

    int LA[2], LB[4];
#pragma unroll
    for (int m = 0; m < 2; ++m) LA[m] = SWZ((wr * 32 + m * 16 + rl) * 64 + q * 16);
#pragma unroll
    for (int n = 0; n < 4; ++n) LB[n] = SWZ((wc * 64 + n * 16 + rl) * 64 + q * 16);

    f32x4 acc[2][4] = {};
    const int NT = K >> 5;

    // prologue: stage K-tile 0 into buf 0
    gl_lds16(gA, &lsa[0][w * 1024]);
    gl_lds16(gB[0], &lsb[0][(w * 2) * 1024]);
    gl_lds16(gB[1], &lsb[0][(w * 2 + 1) * 1024]);
    __syncthreads();   // drains vmcnt(0): tile 0 resident

    int cur = 0;
    for (int kt = 0; kt < NT; ++kt) {
        if (kt + 1 < NT) {   // async issue of next tile; hides under MFMA +
            const int kb = (kt + 1) * 64;   // co-resident block's compute
            gl_lds16(gA + kb, &lsa[cur ^ 1][w * 1024]);
            gl_lds16(gB[0] + kb, &lsb[cur ^ 1][(w * 2) * 1024]);
            gl_lds16(gB[1] + kb, &lsb[cur ^ 1][(w * 2 + 1) * 1024]);
        }
        short8 af[2], bfr[4];
#pragma unroll
        for (int m = 0; m < 2; ++m) af[m] = *(const short8*)(&lsa[cur][LA[m]]);
#pragma unroll
        for (int n = 0; n < 4; ++n) bfr[n] = *(const short8*)(&lsb[cur][LB[n]]);
#pragma unroll
        for (int m = 0; m < 2; ++m)
#pragma unroll
            for (int n = 0; n < 4; ++n)
                acc[m][n] = __builtin_amdgcn_mfma_f32_16x16x32_bf16(
                    af[m], bfr[n], acc[m][n], 0, 0, 0);
        __syncthreads();   // all reads of buf[cur] done; next tile resident
        cur ^= 1;
    }

    float bia[4];
#pragma unroll
    for (int n = 0; n < 4; ++n) {
        int c = col0 + wc * 64 + n * 16 + rl;
        bia[n] = (HAS_BIAS && c < DM) ? bias[c] : 0.f;
    }
#pragma unroll
    for (int m = 0; m < 2; ++m) {
#pragma unroll
        for (int n = 0; n < 4; ++n) {
            int c = col0 + wc * 64 + n * 16 + rl;
#pragma unroll
            for (int i = 0; i < 4; ++i) {
                int r = row0 + wr * 32 + m * 16 + q * 4 + i;
                float v = acc[m][n][i];
                if (PROJMODE == 1 && c >= DM) {
                    if (c < DM + DS)          BpO[(size_t)r * DS + (c - DM)] = v;
                    else if (c < DM + 2 * DS) CpO[(size_t)r * DS + (c - DM - DS)] = v;
                } else if (PROJMODE == 2 && c >= DM) {
                    if (c == DM) BpO[r] = v;
                } else {
                    v += bia[n];
                    if (ACT == 1) v = sp_f(v);
                    if (HAS_RES) v += res[(size_t)r * ldc + c];
                    if (OUTBF) ((ushort_t*)Cout)[(size_t)r * ldc + c] = f2bf(v);
                    else       ((float*)Cout)[(size_t)r * ldc + c] = v;
                }
            }
        }
    }
}

// ---------------------------------------------------------------------------
// Merged prep kernel (region-branched on blockIdx.x; all regions read only
// kernel inputs -> no intra-kernel dependencies).
//  [0,2048)     x fp32 -> x_bf
//  [2048,3072)  W_delta fp32 -> WdX rows [0,1024)
//  [3072,3584)  WdX rows [1024,1152): row 1024 = bf16(delta_base), rest 0
//  [3584,5632)  W_in  [1024][2048] -> WinT [2048][1024]
//  [5632,6656)  W_tau [1024][1024] -> WtT
//  [6656,7680)  W_out [1024][1024] -> WoT
//  [7680,8192)  WdcT rows [1024,1152): W_B^T(16), W_C^T(16), zeros(96)
// ---------------------------------------------------------------------------
static __device__ __forceinline__ void tconv_body(
    const float* __restrict__ in, ushort_t* __restrict__ out,
    int K, int N, int n0, int k0, float (*t)[33], int tid)
{
    int lx = tid & 31, ly = tid >> 5;
#pragma unroll
    for (int i = 0; i < 32; i += 8)
        t[ly + i][lx] = in[(size_t)(k0 + ly + i) * N + n0 + lx];
    __syncthreads();
#pragma unroll
    for (int i = 0; i < 32; i += 8)
        out[(size_t)(n0 + ly + i) * K + k0 + lx] = f2bf(t[lx][ly + i]);
}

__global__ __launch_bounds__(256) void prep_k(
    const float* __restrict__ x, const float* __restrict__ W_in,
    const float* __restrict__ W_B, const float* __restrict__ W_C,
    const float* __restrict__ W_delta, const float* __restrict__ db,
    const float* __restrict__ W_tau, const float* __restrict__ W_out,
    ushort_t* __restrict__ x_bf, ushort_t* __restrict__ WinT,
    ushort_t* __restrict__ WtT, ushort_t* __restrict__ WoT,
    ushort_t* __restrict__ WdX, ushort_t* __restrict__ WdcT)
{
    __shared__ float t[32][33];
    const int blk = blockIdx.x;
    const int tid = threadIdx.x;
    if (blk < 2048) {
        int i = blk * 256 + tid;
        f4 v = ((const f4*)x)[i];
        us4 o; o.x = f2bf(v.x); o.y = f2bf(v.y); o.z = f2bf(v.z); o.w = f2bf(v.w);
        ((us4*)x_bf)[i] = o;
    } else if (blk < 3072) {
        int i = (blk - 2048) * 256 + tid;
        f4 v = ((const f4*)W_delta)[i];
        us4 o; o.x = f2bf(v.x); o.y = f2bf(v.y); o.z = f2bf(v.z); o.w = f2bf(v.w);
        ((us4*)WdX)[i] = o;
    } else if (blk < 3584) {
        int i = (blk - 3072) * 256 + tid;       // 0..131071
        int k = i & 1023, r = i >> 10;          // r 0..127
        WdX[(size_t)(1024 + r) * 1024 + k] = (r == 0) ? f2bf(db[k]) : (ushort_t)0;
    } else if (blk < 5632) {
        int tau = blk - 3584;
        tconv_body(W_in, WinT, 1024, 2048, (tau & 63) * 32, (tau >> 6) * 32, t, tid);
    } else if (blk < 6656) {
        int tau = blk - 5632;
        tconv_body(W_tau, WtT, 1024, 1024, (tau & 31) * 32, (tau >> 5) * 32, t, tid);
    } else if (blk < 7680) {
        int tau = blk - 6656;
        tconv_body(W_out, WoT, 1024, 1024, (tau & 31) * 32, (tau >> 5) * 32, t, tid);
    } else {
        int i = (blk - 7680) * 256 + tid;       // 0..131071
        int k = i & 1023, r = i >> 10;          // r 0..127
        ushort_t v = 0;
        if (r < DS)          v = f2bf(W_B[(size_t)k * DS + r]);
        else if (r < 2 * DS) v = f2bf(W_C[(size_t)k * DS + (r - DS)]);
        WdcT[(size_t)(1024 + r) * 1024 + k] = v;
    }
}

// ---------------------------------------------------------------------------
// Depthwise conv1d (K=3, same padding) + SiLU.  bf16 in (z), bf16 out (val).
// ---------------------------------------------------------------------------
__global__ __launch_bounds__(256) void conv_silu_k(
    const ushort_t* __restrict__ z_bf, const float* __restrict__ cw,
    ushort_t* __restrict__ val_bf)
{
    int t = blockIdx.x * 256 + threadIdx.x;    // ROWS*DI/4
    int c0 = (t & 255) * 4;
    int row = t >> 8;
    int l = row & (LL - 1);
    const ushort_t* zr = z_bf + (size_t)row * (2 * DI) + c0;
    us4 zz = {0, 0, 0, 0};
    us4 vm = (l > 0)      ? *(const us4*)(zr - 2 * DI) : zz;
    us4 v0 = *(const us4*)(zr);
    us4 vp = (l < LL - 1) ? *(const us4*)(zr + 2 * DI) : zz;
    const f4* wp = (const f4*)(cw + (size_t)c0 * 3);
    f4 w0 = wp[0], w1 = wp[1], w2 = wp[2];
    float w[12];
#pragma unroll
    for (int k = 0; k < 4; ++k) { w[k] = w0[k]; w[4 + k] = w1[k]; w[8 + k] = w2[k]; }
    us4 o;
#pragma unroll
    for (int j = 0; j < 4; ++j) {
        float s = bf2f(vm[j]) * w[3 * j] + bf2f(v0[j]) * w[3 * j + 1]
                + bf2f(vp[j]) * w[3 * j + 2];
        float si = s / (1.f + __expf(-s));
        o[j] = f2bf(si);
    }
    *(us4*)(val_bf + (size_t)row * DI + c0) = o;
}

// ---------------------------------------------------------------------------
// Chunked selective scan, thread per (b,d,chunk), 16 n in registers.
// h = a*(h+t) - t with t = (B/A)*u;  a = exp(Delta*A).
// ---------------------------------------------------------------------------
__global__ __launch_bounds__(256) void scan_p1_k(
    const ushort_t* __restrict__ Del_bf, const ushort_t* __restrict__ val_bf,
    const float* __restrict__ Bp, const float* __restrict__ A_log,
    float* __restrict__ aprod, float* __restrict__ hloc)
{
    int t = blockIdx.x * 256 + threadIdx.x;    // BB*NCH*DI = 131072
    int d = t & (DI - 1);
    int c = (t >> 10) & (NCH - 1);
    int b = t >> 16;

    float Adn[DS], ci[DS];
    const f4* alp = (const f4*)(A_log + (size_t)d * DS);
#pragma unroll
    for (int j = 0; j < 4; ++j) {
        f4 al = alp[j];
#pragma unroll
        for (int k = 0; k < 4; ++k) {
            float a = -__expf(al[k]);
            Adn[j * 4 + k] = a;
            ci[j * 4 + k] = 1.0f / a;
        }
    }
    int row0 = b * LL + c * CH;
    const ushort_t* Dp = Del_bf + (size_t)row0 * DI + d;
    const ushort_t* up = val_bf + (size_t)row0 * DI + d;
    const f4* bp = (const f4*)(Bp + (size_t)row0 * DS);

    float h[DS];
#pragma unroll
    for (int n = 0; n < DS; ++n) h[n] = 0.f;
    float sdv = 0.f;

#pragma unroll 2
    for (int l = 0; l < CH; ++l) {
        float dv = bf2f(Dp[(size_t)l * DI]);
        float u  = bf2f(up[(size_t)l * DI]);
        f4 q0 = bp[l * 4 + 0], q1 = bp[l * 4 + 1], q2 = bp[l * 4 + 2], q3 = bp[l * 4 + 3];
        float bn[DS];
#pragma unroll
        for (int k = 0; k < 4; ++k) {
            bn[k] = q0[k]; bn[4 + k] = q1[k]; bn[8 + k] = q2[k]; bn[12 + k] = q3[k];
        }
        sdv += dv;
#pragma unroll
        for (int n = 0; n < DS; ++n) {
            float a  = __expf(dv * Adn[n]);
            float tt = (ci[n] * bn[n]) * u;
            float s  = h[n] + tt;
            h[n] = fmaf(a, s, -tt);
        }
    }
    size_t o = (((size_t)b * NCH + c) * DI + d) * DS;
#pragma unroll
    for (int j = 0; j < 4; ++j) {
        f4 hv, av;
#pragma unroll
        for (int k = 0; k < 4; ++k) {
            hv[k] = h[j * 4 + k];
            av[k] = __expf(sdv * Adn[j * 4 + k]);
        }
        *(f4*)(hloc + o + j * 4) = hv;
        *(f4*)(aprod + o + j * 4) = av;
    }
}

__global__ __launch_bounds__(256) void scan_p2_k(
    const float* __restrict__ aprod, const float* __restrict__ hloc,
    float* __restrict__ hin)
{
    int t = blockIdx.x * 256 + threadIdx.x;    // BB*DI*DS = 32768
    int dn = t & (DI * DS - 1);
    int b = t >> 14;
    float h = 0.f;
    size_t base = (size_t)b * NCH * DI * DS + dn;
#pragma unroll 4
    for (int c = 0; c < NCH; ++c) {
        size_t idx = base + (size_t)c * (DI * DS);
        hin[idx] = h;
        h = fmaf(aprod[idx], h, hloc[idx]);
    }
}

// phase 3: recompute with correct h_in; fused gate: g_bf = bf16(y * silu(zgate))
__global__ __launch_bounds__(256) void scan_p3_k(
    const ushort_t* __restrict__ Del_bf, const ushort_t* __restrict__ val_bf,
    const float* __restrict__ Bp, const float* __restrict__ Cp,
    const float* __restrict__ A_log, const float* __restrict__ hin,
    const ushort_t* __restrict__ z_bf, ushort_t* __restrict__ g_bf)
{
    int t = blockIdx.x * 256 + threadIdx.x;    // BB*NCH*DI
    int d = t & (DI - 1);
    int c = (t >> 10) & (NCH - 1);
    int b = t >> 16;

    float Adn[DS], ci[DS];
    const f4* alp = (const f4*)(A_log + (size_t)d * DS);
#pragma unroll
    for (int j = 0; j < 4; ++j) {
        f4 al = alp[j];
#pragma unroll
        for (int k = 0; k < 4; ++k) {
            float a = -__expf(al[k]);
            Adn[j * 4 + k] = a;
            ci[j * 4 + k] = 1.0f / a;
        }
    }
    int row0 = b * LL + c * CH;
    const ushort_t* Dp = Del_bf + (size_t)row0 * DI + d;
    const ushort_t* up = val_bf + (size_t)row0 * DI + d;
    const ushort_t* zp = z_bf + (size_t)row0 * (2 * DI) + DI + d;
    const f4* bp = (const f4*)(Bp + (size_t)row0 * DS);
    const f4* cp = (const f4*)(Cp + (size_t)row0 * DS);
    ushort_t* gp = g_bf + (size_t)row0 * DI + d;

    float h[DS];
    size_t o = (((size_t)b * NCH + c) * DI + d) * DS;
#pragma unroll
    for (int j = 0; j < 4; ++j) {
        f4 hv = *(const f4*)(hin + o + j * 4);
#pragma unroll
        for (int k = 0; k < 4; ++k) h[j * 4 + k] = hv[k];
    }

#pragma unroll 2
    for (int l = 0; l < CH; ++l) {
        float dv = bf2f(Dp[(size_t)l * DI]);
        float u  = bf2f(up[(size_t)l * DI]);
        f4 q0 = bp[l * 4 + 0], q1 = bp[l * 4 + 1], q2 = bp[l * 4 + 2], q3 = bp[l * 4 + 3];
        f4 r0 = cp[l * 4 + 0], r1 = cp[l * 4 + 1], r2 = cp[l * 4 + 2], r3 = cp[l * 4 + 3];
        float bn[DS], cn[DS];
#pragma unroll
        for (int k = 0; k < 4; ++k) {
            bn[k] = q0[k]; bn[4 + k] = q1[k]; bn[8 + k] = q2[k]; bn[12 + k] = q3[k];
            cn[k] = r0[k]; cn[4 + k] = r1[k]; cn[8 + k] = r2[k]; cn[12 + k] = r3[k];
        }
        float psum = 0.f;
#pragma unroll
        for (int n = 0; n < DS; ++n) {
            float a  = __expf(dv * Adn[n]);
            float tt = (ci[n] * bn[n]) * u;
            float s  = h[n] + tt;
            h[n] = fmaf(a, s, -tt);
            psum = fmaf(h[n], cn[n], psum);
        }
        float zg = bf2f(zp[(size_t)l * 2 * DI]);
        float si = zg / (1.f + __expf(-zg));
        gp[(size_t)l * DI] = f2bf(psum * si);
    }
}

// ---------------------------------------------------------------------------
extern "C" void kernel_launch(void* const* d_in, const int* in_sizes, int n_in,
                              void* d_out, int out_size, void* d_ws, size_t ws_size,
                              hipStream_t stream)
{
    (void)in_sizes; (void)n_in; (void)out_size; (void)ws_size;

    const float* x        = (const float*)d_in[0];
    const float* W_in     = (const float*)d_in[1];
    const float* conv_w   = (const float*)d_in[2];
    const float* W_B      = (const float*)d_in[3];
    const float* W_C      = (const float*)d_in[4];
    const float* W_delta  = (const float*)d_in[5];
    const float* delta_b  = (const float*)d_in[6];
    const float* W_tau    = (const float*)d_in[7];
    const float* A_log    = (const float*)d_in[8];
    const float* W_out    = (const float*)d_in[9];
    float* out = (float*)d_out;

    const size_t M1 = 1024 * 1024;
    ushort_t* us = (ushort_t*)d_ws;
    ushort_t* z_bf   = us;                    // 4M ushort
    ushort_t* val_bf = us + 4 * M1;           // 2M
    ushort_t* Del_bf = us + 6 * M1;           // 2M
    ushort_t* x_bf   = us + 8 * M1;           // 2M
    ushort_t* g_bf   = us + 10 * M1;          // 2M
    ushort_t* WinT   = us + 12 * M1;          // 2M
    ushort_t* WoT    = us + 14 * M1;          // 1M
    ushort_t* WtT    = us + 15 * M1;          // 1M
    ushort_t* WdX    = us + 16 * M1;          // NF*1024 = 1,179,648
    ushort_t* WdcT   = WdX + (size_t)NF * 1024;   // NP*1024 (~38.3MB end)
    float* fb    = (float*)(us + 20 * M1);    // 40MB offset
    float* Bp    = fb;                         // 32768
    float* Cp    = fb + (size_t)ROWS * DS;     // 32768
    float* b2    = fb + 2 * (size_t)ROWS * DS; // 1024
    float* aprod = b2 + 1024;                  // 2M fl
    float* hloc  = aprod + 2 * M1;             // 2M fl
    float* hin   = hloc + 2 * M1;              // 2M fl (~64.3MB end)

    // 0) merged prep: converts, transposes, tail rows
    prep_k<<<8192, 256, 0, stream>>>(x, W_in, W_B, W_C, W_delta, delta_b,
                                     W_tau, W_out, x_bf, WinT, WtT, WoT, WdX, WdcT);

    // 0b) fused weight: WdcT[n][i] = sum_m WtT[n][m]*WdX[i][m]; col 1024 -> b2
    gemm_bf_k<0, false, false, true, 2><<<dim3(NF / 128, DM / 64), 256, 0, stream>>>(
        WtT, WdX, nullptr, nullptr, WdcT, b2, nullptr, DM, NF, DM, DM);

    // 1) z = x @ W_in  (bf16 out)
    gemm_bf_k<0, false, false, true, 0><<<dim3(2 * DI / 128, ROWS / 64), 256, 0, stream>>>(
        x_bf, WinT, nullptr, nullptr, z_bf, nullptr, nullptr, ROWS, 2 * DI, DM, 2 * DI);

    // 2) val = silu(conv1d(z[:, :DI]))
    conv_silu_k<<<(ROWS * DI / 4) / 256, 256, 0, stream>>>(z_bf, conv_w, val_bf);

    // 3) Delta = softplus(val @ Wfused + b2) -> Del_bf; fused B/C proj -> Bp,Cp
    gemm_bf_k<1, true, false, true, 1><<<dim3(NP / 128, ROWS / 64), 256, 0, stream>>>(
        val_bf, WdcT, b2, nullptr, Del_bf, Bp, Cp, ROWS, NP, DI, DM);

    // 4) chunked selective scan; p3 fuses gate -> g_bf
    scan_p1_k<<<(BB * NCH * DI) / 256, 256, 0, stream>>>(
        Del_bf, val_bf, Bp, A_log, aprod, hloc);
    scan_p2_k<<<(BB * DI * DS) / 256, 256, 0, stream>>>(aprod, hloc, hin);
    scan_p3_k<<<(BB * NCH * DI) / 256, 256, 0, stream>>>(
        Del_bf, val_bf, Bp, Cp, A_log, hin, z_bf, g_bf);

    // 5) out = g @ W_out + x (fp32 out)
    gemm_bf_k<0, false, true, false, 0><<<dim3(DM / 128, ROWS / 64), 256, 0, stream>>>(
        g_bf, WoT, nullptr, x, out, nullptr, nullptr, ROWS, DM, DI, DM);
}

// Round 10
// 231.249 us; speedup vs baseline: 1.4689x; 1.0372x over previous
//
#include <hip/hip_runtime.h>
#include <math.h>

// Problem constants (MambaBlock reference)
#define BB 2
#define LL 1024
#define DM 1024
#define DI 1024
#define DS 16
#define ROWS (BB * LL)   // 2048
#define CH 16            // scan chunk length
#define NCH (LL / CH)    // 64 chunks
#define NP 1152          // main GEMM N: 1024 Delta + 16 B + 16 C + 96 zero pad
#define NF 1152          // fuse GEMM N: 1024 W_delta rows + 1 delta_base + 127 pad

typedef unsigned short ushort_t;
typedef __attribute__((ext_vector_type(8))) short short8;
typedef __attribute__((ext_vector_type(4))) float f32x4;
typedef __attribute__((ext_vector_type(4))) float f4;
typedef __attribute__((ext_vector_type(4))) ushort_t us4;

static __device__ __forceinline__ float sp_f(float x) {
    return fmaxf(x, 0.f) + log1pf(expf(-fabsf(x)));
}
static __device__ __forceinline__ ushort_t f2bf(float f) {
    unsigned u = __float_as_uint(f);
    u += 0x7fffu + ((u >> 16) & 1u);
    return (ushort_t)(u >> 16);
}
static __device__ __forceinline__ float bf2f(ushort_t s) {
    return __uint_as_float(((unsigned)s) << 16);
}

// LDS XOR swizzle for 128B rows (BK=64 bf16): flip byte-bits 4..6 keyed by
// row bits 0..2 (addr bits 7..9).  Involution.  Applied to the global source
// of global_load_lds (linear LDS dest) AND to ds_read fragment addresses
// (both-sides rule, §5.5 T21 / m173).
#define SWZ(L) ((L) ^ ((((L) >> 7) & 7) << 4))

static __device__ __forceinline__ void gl_lds16(const void* g, void* l) {
    __builtin_amdgcn_global_load_lds(
        (const __attribute__((address_space(1))) unsigned int*)g,
        (__attribute__((address_space(3))) unsigned int*)l, 16, 0, 0);
}

// ---------------------------------------------------------------------------
// bf16 MFMA GEMM: C[M,N] = epi(A[M,K] @ Bt[N,K]^T), output stride ldc.
// 64x128 tile, BK=64, 256 threads (4 waves 2x2, each 32x64 -> acc[2][4]).
// T3/T4-minimum pipeline: counted s_waitcnt vmcnt(6) + raw s_barrier instead
// of __syncthreads' vmcnt(0) drain -- prefetch loads stay in flight across
// the barrier (the R9 structure drained its own prefetch every iteration).
// PROJMODE 0: plain epilogue.  1: cols>=DM -> Bp/Cp (fp32).  2: col==DM -> b2.
// ---------------------------------------------------------------------------
template <int ACT, bool HAS_BIAS, bool HAS_RES, bool OUTBF, int PROJMODE>
__global__ __launch_bounds__(256) void gemm_bf_k(
    const ushort_t* __restrict__ A, const ushort_t* __restrict__ Bt,
    const float* __restrict__ bias, const float* __restrict__ res,
    void* __restrict__ Cout, float* __restrict__ BpO, float* __restrict__ CpO,
    int M, int N, int K, int ldc)
{
    __shared__ __align__(16) char lsa[2][8192];    // A tile [64][64] bf16
    __shared__ __align__(16) char lsb[2][16384];   // B tile [128][64] bf16

    const int tid = threadIdx.x;
    const int lane = tid & 63;
    const int w = tid >> 6;
    const int wr = w >> 1, wc = w & 1;

    // XCD-aware bijective swizzle (T1): all launches have nwg % 8 == 0.
    int wg = blockIdx.y * gridDim.x + blockIdx.x;
    const int nwg = gridDim.x * gridDim.y;
    wg = (wg & 7) * (nwg >> 3) + (wg >> 3);
    const int bx = wg % gridDim.x, by = wg / gridDim.x;
    const int row0 = by * 64, col0 = bx * 128;

    const int rl = lane & 15, q = lane >> 4;

    // per-lane pre-swizzled global sources (bytes); LDS dest is linear.
    // A: 8KB = 2 wave-insts/wave; B: 16KB = 4 wave-insts/wave.
    const char* gA[2];
#pragma unroll
    for (int j = 0; j < 2; ++j) {
        int L = SWZ((w * 2 + j) * 1024 + lane * 16);
        gA[j] = (const char*)A + ((size_t)(row0 + (L >> 7)) * K) * 2 + (L & 127);
    }
    const char* gB[4];
#pragma unroll
    for (int j = 0; j < 4; ++j) {
        int L = SWZ((w * 4 + j) * 1024 + lane * 16);
        gB[j] = (const char*)Bt + ((size_t)(col0 + (L >> 7)) * K) * 2 + (L & 127);
    }

    int LA[2][2], LB[4][2];
#pragma unroll
    for (int m = 0; m < 2; ++m)
#pragma unroll
        for (int kk = 0; kk < 2; ++kk)
            LA[m][kk] = SWZ((wr * 32 + m * 16 + rl) * 128 + kk * 64 + q * 16);
#pragma unroll
    for (int n = 0; n < 4; ++n)
#pragma unroll
        for (int kk = 0; kk < 2; ++kk)
            LB[n][kk] = SWZ((wc * 64 + n * 16 + rl) * 128 + kk * 64 + q * 16);

    f32x4 acc[2][4] = {};
    const int NT = K >> 6;   // BK = 64

    // prologue: stage K-tile 0 into buf 0 (6 gl_lds per wave)
#pragma unroll
    for (int j = 0; j < 2; ++j) gl_lds16(gA[j], &lsa[0][(w * 2 + j) * 1024]);
#pragma unroll
    for (int j = 0; j < 4; ++j) gl_lds16(gB[j], &lsb[0][(w * 4 + j) * 1024]);

    int cur = 0;
    for (int kt = 0; kt < NT; ++kt) {
        if (kt + 1 < NT) {
            // issue next tile (stays in flight across the barrier: vmcnt(6))
            const int kb = (kt + 1) * 128;
#pragma unroll
            for (int j = 0; j < 2; ++j)
                gl_lds16(gA[j] + kb, &lsa[cur ^ 1][(w * 2 + j) * 1024]);
#pragma unroll
            for (int j = 0; j < 4; ++j)
                gl_lds16(gB[j] + kb, &lsb[cur ^ 1][(w * 4 + j) * 1024]);
            asm volatile("s_waitcnt vmcnt(6)\n\ts_barrier" ::: "memory");
        } else {
            asm volatile("s_waitcnt vmcnt(0)\n\ts_barrier" ::: "memory");
        }
        short8 af[2][2], bfr[4][2];
#pragma unroll
        for (int m = 0; m < 2; ++m)
#pragma unroll
            for (int kk = 0; kk < 2; ++kk)
                af[m][kk] = *(const short8*)(&lsa[cur][LA[m][kk]]);
#pragma unroll
        for (int n = 0; n < 4; ++n)
#pragma unroll
            for (int kk = 0; kk < 2; ++kk)
                bfr[n][kk] = *(const short8*)(&lsb[cur][LB[n][kk]]);
#pragma unroll
        for (int kk = 0; kk < 2; ++kk)
#pragma unroll
            for (int m = 0; m < 2; ++m)
#pragma unroll
                for (int n = 0; n < 4; ++n)
                    acc[m][n] = __builtin_amdgcn_mfma_f32_16x16x32_bf16(
                        af[m][kk], bfr[n][kk], acc[m][n], 0, 0, 0);
        // all waves done reading buf[cur] before next iter's prefetch overwrites
        asm volatile("s_barrier" ::: "memory");
        cur ^= 1;
    }

    float bia[4];
#pragma unroll
    for (int n = 0; n < 4; ++n) {
        int c = col0 + wc * 64 + n * 16 + rl;
        bia[n] = (HAS_BIAS && c < DM) ? bias[c] : 0.f;
    }
#pragma unroll
    for (int m = 0; m < 2; ++m) {
#pragma unroll
        for (int n = 0; n < 4; ++n) {
            int c = col0 + wc * 64 + n * 16 + rl;
#pragma unroll
            for (int i = 0; i < 4; ++i) {
                int r = row0 + wr * 32 + m * 16 + q * 4 + i;
                float v = acc[m][n][i];
                if (PROJMODE == 1 && c >= DM) {
                    if (c < DM + DS)          BpO[(size_t)r * DS + (c - DM)] = v;
                    else if (c < DM + 2 * DS) CpO[(size_t)r * DS + (c - DM - DS)] = v;
                } else if (PROJMODE == 2 && c >= DM) {
                    if (c == DM) BpO[r] = v;
                } else {
                    v += bia[n];
                    if (ACT == 1) v = sp_f(v);
                    if (HAS_RES) v += res[(size_t)r * ldc + c];
                    if (OUTBF) ((ushort_t*)Cout)[(size_t)r * ldc + c] = f2bf(v);
                    else       ((float*)Cout)[(size_t)r * ldc + c] = v;
                }
            }
        }
    }
}

// ---------------------------------------------------------------------------
// Merged prep kernel (region-branched on blockIdx.x; all regions read only
// kernel inputs -> no intra-kernel dependencies).
// ---------------------------------------------------------------------------
static __device__ __forceinline__ void tconv_body(
    const float* __restrict__ in, ushort_t* __restrict__ out,
    int K, int N, int n0, int k0, float (*t)[33], int tid)
{
    int lx = tid & 31, ly = tid >> 5;
#pragma unroll
    for (int i = 0; i < 32; i += 8)
        t[ly + i][lx] = in[(size_t)(k0 + ly + i) * N + n0 + lx];
    __syncthreads();
#pragma unroll
    for (int i = 0; i < 32; i += 8)
        out[(size_t)(n0 + ly + i) * K + k0 + lx] = f2bf(t[lx][ly + i]);
}

__global__ __launch_bounds__(256) void prep_k(
    const float* __restrict__ x, const float* __restrict__ W_in,
    const float* __restrict__ W_B, const float* __restrict__ W_C,
    const float* __restrict__ W_delta, const float* __restrict__ db,
    const float* __restrict__ W_tau, const float* __restrict__ W_out,
    ushort_t* __restrict__ x_bf, ushort_t* __restrict__ WinT,
    ushort_t* __restrict__ WtT, ushort_t* __restrict__ WoT,
    ushort_t* __restrict__ WdX, ushort_t* __restrict__ WdcT)
{
    __shared__ float t[32][33];
    const int blk = blockIdx.x;
    const int tid = threadIdx.x;
    if (blk < 2048) {
        int i = blk * 256 + tid;
        f4 v = ((const f4*)x)[i];
        us4 o; o.x = f2bf(v.x); o.y = f2bf(v.y); o.z = f2bf(v.z); o.w = f2bf(v.w);
        ((us4*)x_bf)[i] = o;
    } else if (blk < 3072) {
        int i = (blk - 2048) * 256 + tid;
        f4 v = ((const f4*)W_delta)[i];
        us4 o; o.x = f2bf(v.x); o.y = f2bf(v.y); o.z = f2bf(v.z); o.w = f2bf(v.w);
        ((us4*)WdX)[i] = o;
    } else if (blk < 3584) {
        int i = (blk - 3072) * 256 + tid;       // 0..131071
        int k = i & 1023, r = i >> 10;          // r 0..127
        WdX[(size_t)(1024 + r) * 1024 + k] = (r == 0) ? f2bf(db[k]) : (ushort_t)0;
    } else if (blk < 5632) {
        int tau = blk - 3584;
        tconv_body(W_in, WinT, 1024, 2048, (tau & 63) * 32, (tau >> 6) * 32, t, tid);
    } else if (blk < 6656) {
        int tau = blk - 5632;
        tconv_body(W_tau, WtT, 1024, 1024, (tau & 31) * 32, (tau >> 5) * 32, t, tid);
    } else if (blk < 7680) {
        int tau = blk - 6656;
        tconv_body(W_out, WoT, 1024, 1024, (tau & 31) * 32, (tau >> 5) * 32, t, tid);
    } else {
        int i = (blk - 7680) * 256 + tid;       // 0..131071
        int k = i & 1023, r = i >> 10;          // r 0..127
        ushort_t v = 0;
        if (r < DS)          v = f2bf(W_B[(size_t)k * DS + r]);
        else if (r < 2 * DS) v = f2bf(W_C[(size_t)k * DS + (r - DS)]);
        WdcT[(size_t)(1024 + r) * 1024 + k] = v;
    }
}

// ---------------------------------------------------------------------------
// Depthwise conv1d (K=3, same padding) + SiLU.  bf16 in (z), bf16 out (val).
// ---------------------------------------------------------------------------
__global__ __launch_bounds__(256) void conv_silu_k(
    const ushort_t* __restrict__ z_bf, const float* __restrict__ cw,
    ushort_t* __restrict__ val_bf)
{
    int t = blockIdx.x * 256 + threadIdx.x;    // ROWS*DI/4
    int c0 = (t & 255) * 4;
    int row = t >> 8;
    int l = row & (LL - 1);
    const ushort_t* zr = z_bf + (size_t)row * (2 * DI) + c0;
    us4 zz = {0, 0, 0, 0};
    us4 vm = (l > 0)      ? *(const us4*)(zr - 2 * DI) : zz;
    us4 v0 = *(const us4*)(zr);
    us4 vp = (l < LL - 1) ? *(const us4*)(zr + 2 * DI) : zz;
    const f4* wp = (const f4*)(cw + (size_t)c0 * 3);
    f4 w0 = wp[0], w1 = wp[1], w2 = wp[2];
    float w[12];
#pragma unroll
    for (int k = 0; k < 4; ++k) { w[k] = w0[k]; w[4 + k] = w1[k]; w[8 + k] = w2[k]; }
    us4 o;
#pragma unroll
    for (int j = 0; j < 4; ++j) {
        float s = bf2f(vm[j]) * w[3 * j] + bf2f(v0[j]) * w[3 * j + 1]
                + bf2f(vp[j]) * w[3 * j + 2];
        float si = s / (1.f + __expf(-s));
        o[j] = f2bf(si);
    }
    *(us4*)(val_bf + (size_t)row * DI + c0) = o;
}

// ---------------------------------------------------------------------------
// Chunked selective scan, thread per (b,d,chunk), 16 n in registers.
// h = a*(h+t) - t with t = (B/A)*u;  a = exp(Delta*A).
// ---------------------------------------------------------------------------
__global__ __launch_bounds__(256) void scan_p1_k(
    const ushort_t* __restrict__ Del_bf, const ushort_t* __restrict__ val_bf,
    const float* __restrict__ Bp, const float* __restrict__ A_log,
    float* __restrict__ aprod, float* __restrict__ hloc)
{
    int t = blockIdx.x * 256 + threadIdx.x;    // BB*NCH*DI = 131072
    int d = t & (DI - 1);
    int c = (t >> 10) & (NCH - 1);
    int b = t >> 16;

    float Adn[DS], ci[DS];
    const f4* alp = (const f4*)(A_log + (size_t)d * DS);
#pragma unroll
    for (int j = 0; j < 4; ++j) {
        f4 al = alp[j];
#pragma unroll
        for (int k = 0; k < 4; ++k) {
            float a = -__expf(al[k]);
            Adn[j * 4 + k] = a;
            ci[j * 4 + k] = 1.0f / a;
        }
    }
    int row0 = b * LL + c * CH;
    const ushort_t* Dp = Del_bf + (size_t)row0 * DI + d;
    const ushort_t* up = val_bf + (size_t)row0 * DI + d;
    const f4* bp = (const f4*)(Bp + (size_t)row0 * DS);

    float h[DS];
#pragma unroll
    for (int n = 0; n < DS; ++n) h[n] = 0.f;
    float sdv = 0.f;

#pragma unroll 2
    for (int l = 0; l < CH; ++l) {
        float dv = bf2f(Dp[(size_t)l * DI]);
        float u  = bf2f(up[(size_t)l * DI]);
        f4 q0 = bp[l * 4 + 0], q1 = bp[l * 4 + 1], q2 = bp[l * 4 + 2], q3 = bp[l * 4 + 3];
        float bn[DS];
#pragma unroll
        for (int k = 0; k < 4; ++k) {
            bn[k] = q0[k]; bn[4 + k] = q1[k]; bn[8 + k] = q2[k]; bn[12 + k] = q3[k];
        }
        sdv += dv;
#pragma unroll
        for (int n = 0; n < DS; ++n) {
            float a  = __expf(dv * Adn[n]);
            float tt = (ci[n] * bn[n]) * u;
            float s  = h[n] + tt;
            h[n] = fmaf(a, s, -tt);
        }
    }
    size_t o = (((size_t)b * NCH + c) * DI + d) * DS;
#pragma unroll
    for (int j = 0; j < 4; ++j) {
        f4 hv, av;
#pragma unroll
        for (int k = 0; k < 4; ++k) {
            hv[k] = h[j * 4 + k];
            av[k] = __expf(sdv * Adn[j * 4 + k]);
        }
        *(f4*)(hloc + o + j * 4) = hv;
        *(f4*)(aprod + o + j * 4) = av;
    }
}

__global__ __launch_bounds__(256) void scan_p2_k(
    const float* __restrict__ aprod, const float* __restrict__ hloc,
    float* __restrict__ hin)
{
    int t = blockIdx.x * 256 + threadIdx.x;    // BB*DI*DS = 32768
    int dn = t & (DI * DS - 1);
    int b = t >> 14;
    float h = 0.f;
    size_t base = (size_t)b * NCH * DI * DS + dn;
#pragma unroll 4
    for (int c = 0; c < NCH; ++c) {
        size_t idx = base + (size_t)c * (DI * DS);
        hin[idx] = h;
        h = fmaf(aprod[idx], h, hloc[idx]);
    }
}

// phase 3: recompute with correct h_in; fused gate: g_bf = bf16(y * silu(zgate))
__global__ __launch_bounds__(256) void scan_p3_k(
    const ushort_t* __restrict__ Del_bf, const ushort_t* __restrict__ val_bf,
    const float* __restrict__ Bp, const float* __restrict__ Cp,
    const float* __restrict__ A_log, const float* __restrict__ hin,
    const ushort_t* __restrict__ z_bf, ushort_t* __restrict__ g_bf)
{
    int t = blockIdx.x * 256 + threadIdx.x;    // BB*NCH*DI
    int d = t & (DI - 1);
    int c = (t >> 10) & (NCH - 1);
    int b = t >> 16;

    float Adn[DS], ci[DS];
    const f4* alp = (const f4*)(A_log + (size_t)d * DS);
#pragma unroll
    for (int j = 0; j < 4; ++j) {
        f4 al = alp[j];
#pragma unroll
        for (int k = 0; k < 4; ++k) {
            float a = -__expf(al[k]);
            Adn[j * 4 + k] = a;
            ci[j * 4 + k] = 1.0f / a;
        }
    }
    int row0 = b * LL + c * CH;
    const ushort_t* Dp = Del_bf + (size_t)row0 * DI + d;
    const ushort_t* up = val_bf + (size_t)row0 * DI + d;
    const ushort_t* zp = z_bf + (size_t)row0 * (2 * DI) + DI + d;
    const f4* bp = (const f4*)(Bp + (size_t)row0 * DS);
    const f4* cp = (const f4*)(Cp + (size_t)row0 * DS);
    ushort_t* gp = g_bf + (size_t)row0 * DI + d;

    float h[DS];
    size_t o = (((size_t)b * NCH + c) * DI + d) * DS;
#pragma unroll
    for (int j = 0; j < 4; ++j) {
        f4 hv = *(const f4*)(hin + o + j * 4);
#pragma unroll
        for (int k = 0; k < 4; ++k) h[j * 4 + k] = hv[k];
    }

#pragma unroll 2
    for (int l = 0; l < CH; ++l) {
        float dv = bf2f(Dp[(size_t)l * DI]);
        float u  = bf2f(up[(size_t)l * DI]);
        f4 q0 = bp[l * 4 + 0], q1 = bp[l * 4 + 1], q2 = bp[l * 4 + 2], q3 = bp[l * 4 + 3];
        f4 r0 = cp[l * 4 + 0], r1 = cp[l * 4 + 1], r2 = cp[l * 4 + 2], r3 = cp[l * 4 + 3];
        float bn[DS], cn[DS];
#pragma unroll
        for (int k = 0; k < 4; ++k) {
            bn[k] = q0[k]; bn[4 + k] = q1[k]; bn[8 + k] = q2[k]; bn[12 + k] = q3[k];
            cn[k] = r0[k]; cn[4 + k] = r1[k]; cn[8 + k] = r2[k]; cn[12 + k] = r3[k];
        }
        float psum = 0.f;
#pragma unroll
        for (int n = 0; n < DS; ++n) {
            float a  = __expf(dv * Adn[n]);
            float tt = (ci[n] * bn[n]) * u;
            float s  = h[n] + tt;
            h[n] = fmaf(a, s, -tt);
            psum = fmaf(h[n], cn[n], psum);
        }
        float zg = bf2f(zp[(size_t)l * 2 * DI]);
        float si = zg / (1.f + __expf(-zg));
        gp[(size_t)l * DI] = f2bf(psum * si);
    }
}

// ---------------------------------------------------------------------------
extern "C" void kernel_launch(void* const* d_in, const int* in_sizes, int n_in,
                              void* d_out, int out_size, void* d_ws, size_t ws_size,
                              hipStream_t stream)
{
    (void)in_sizes; (void)n_in; (void)out_size; (void)ws_size;

    const float* x        = (const float*)d_in[0];
    const float* W_in     = (const float*)d_in[1];
    const float* conv_w   = (const float*)d_in[2];
    const float* W_B      = (const float*)d_in[3];
    const float* W_C      = (const float*)d_in[4];
    const float* W_delta  = (const float*)d_in[5];
    const float* delta_b  = (const float*)d_in[6];
    const float* W_tau    = (const float*)d_in[7];
    const float* A_log    = (const float*)d_in[8];
    const float* W_out    = (const float*)d_in[9];
    float* out = (float*)d_out;

    const size_t M1 = 1024 * 1024;
    ushort_t* us = (ushort_t*)d_ws;
    ushort_t* z_bf   = us;                    // 4M ushort
    ushort_t* val_bf = us + 4 * M1;           // 2M
    ushort_t* Del_bf = us + 6 * M1;           // 2M
    ushort_t* x_bf   = us + 8 * M1;           // 2M
    ushort_t* g_bf   = us + 10 * M1;          // 2M
    ushort_t* WinT   = us + 12 * M1;          // 2M
    ushort_t* WoT    = us + 14 * M1;          // 1M
    ushort_t* WtT    = us + 15 * M1;          // 1M
    ushort_t* WdX    = us + 16 * M1;          // NF*1024 = 1,179,648
    ushort_t* WdcT   = WdX + (size_t)NF * 1024;   // NP*1024 (~38.3MB end)
    float* fb    = (float*)(us + 20 * M1);    // 40MB offset
    float* Bp    = fb;                         // 32768
    float* Cp    = fb + (size_t)ROWS * DS;     // 32768
    float* b2    = fb + 2 * (size_t)ROWS * DS; // 1024
    float* aprod = b2 + 1024;                  // 2M fl
    float* hloc  = aprod + 2 * M1;             // 2M fl
    float* hin   = hloc + 2 * M1;              // 2M fl (~64.3MB end)

    // 0) merged prep: converts, transposes, tail rows
    prep_k<<<8192, 256, 0, stream>>>(x, W_in, W_B, W_C, W_delta, delta_b,
                                     W_tau, W_out, x_bf, WinT, WtT, WoT, WdX, WdcT);

    // 0b) fused weight: WdcT[n][i] = sum_m WtT[n][m]*WdX[i][m]; col 1024 -> b2
    gemm_bf_k<0, false, false, true, 2><<<dim3(NF / 128, DM / 64), 256, 0, stream>>>(
        WtT, WdX, nullptr, nullptr, WdcT, b2, nullptr, DM, NF, DM, DM);

    // 1) z = x @ W_in  (bf16 out)
    gemm_bf_k<0, false, false, true, 0><<<dim3(2 * DI / 128, ROWS / 64), 256, 0, stream>>>(
        x_bf, WinT, nullptr, nullptr, z_bf, nullptr, nullptr, ROWS, 2 * DI, DM, 2 * DI);

    // 2) val = silu(conv1d(z[:, :DI]))
    conv_silu_k<<<(ROWS * DI / 4) / 256, 256, 0, stream>>>(z_bf, conv_w, val_bf);

    // 3) Delta = softplus(val @ Wfused + b2) -> Del_bf; fused B/C proj -> Bp,Cp
    gemm_bf_k<1, true, false, true, 1><<<dim3(NP / 128, ROWS / 64), 256, 0, stream>>>(
        val_bf, WdcT, b2, nullptr, Del_bf, Bp, Cp, ROWS, NP, DI, DM);

    // 4) chunked selective scan; p3 fuses gate -> g_bf
    scan_p1_k<<<(BB * NCH * DI) / 256, 256, 0, stream>>>(
        Del_bf, val_bf, Bp, A_log, aprod, hloc);
    scan_p2_k<<<(BB * DI * DS) / 256, 256, 0, stream>>>(aprod, hloc, hin);
    scan_p3_k<<<(BB * NCH * DI) / 256, 256, 0, stream>>>(
        Del_bf, val_bf, Bp, Cp, A_log, hin, z_bf, g_bf);

    // 5) out = g @ W_out + x (fp32 out)
    gemm_bf_k<0, false, true, false, 0><<<dim3(DM / 128, ROWS / 64), 256, 0, stream>>>(
        g_bf, WoT, nullptr, x, out, nullptr, nullptr, ROWS, DM, DI, DM);
}

// Round 12
// 220.362 us; speedup vs baseline: 1.5414x; 1.0494x over previous
//
#include <hip/hip_runtime.h>
#include <math.h>

// Problem constants (MambaBlock reference)
#define BB 2
#define LL 1024
#define DM 1024
#define DI 1024
#define DS 16
#define ROWS (BB * LL)   // 2048
#define CH 16            // scan chunk length
#define NCH (LL / CH)    // 64 chunks
#define NP 1152          // main GEMM N: 1024 Delta + 16 B + 16 C + 96 zero pad
#define NF 1152          // fuse GEMM N: 1024 W_delta rows + 1 delta_base + 127 pad

typedef unsigned short ushort_t;
typedef __attribute__((ext_vector_type(8))) short short8;
typedef __attribute__((ext_vector_type(4))) float f32x4;
typedef __attribute__((ext_vector_type(4))) float f4;
typedef __attribute__((ext_vector_type(4))) ushort_t us4;

static __device__ __forceinline__ float sp_f(float x) {
    return fmaxf(x, 0.f) + log1pf(expf(-fabsf(x)));
}
static __device__ __forceinline__ ushort_t f2bf(float f) {
    unsigned u = __float_as_uint(f);
    u += 0x7fffu + ((u >> 16) & 1u);
    return (ushort_t)(u >> 16);
}
static __device__ __forceinline__ float bf2f(ushort_t s) {
    return __uint_as_float(((unsigned)s) << 16);
}

// LDS XOR swizzle for 128B rows (BK=64 bf16): flip byte-bits 4..6 keyed by
// row bits 0..2 (addr bits 7..9).  Involution.  (both-sides rule, T21/m173)
#define SWZ(L) ((L) ^ ((((L) >> 7) & 7) << 4))

static __device__ __forceinline__ void gl_lds16(const void* g, void* l) {
    __builtin_amdgcn_global_load_lds(
        (const __attribute__((address_space(1))) unsigned int*)g,
        (__attribute__((address_space(3))) unsigned int*)l, 16, 0, 0);
}

// ---------------------------------------------------------------------------
// bf16 MFMA GEMM: C[M,N] = epi(A[M,K] @ Bt[N,K]^T), output stride ldc.
// 64x128 tile, BK=64, 256 threads; counted vmcnt(6) pipeline (R10 structure).
// PROJMODE 0: plain epilogue.  1: cols>=DM -> Bp/Cp (fp32).  2: col==DM -> b2.
// ---------------------------------------------------------------------------
template <int ACT, bool HAS_BIAS, bool HAS_RES, bool OUTBF, int PROJMODE>
__global__ __launch_bounds__(256) void gemm_bf_k(
    const ushort_t* __restrict__ A, const ushort_t* __restrict__ Bt,
    const float* __restrict__ bias, const float* __restrict__ res,
    void* __restrict__ Cout, float* __restrict__ BpO, float* __restrict__ CpO,
    int M, int N, int K, int ldc)
{
    __shared__ __align__(16) char lsa[2][8192];    // A tile [64][64] bf16
    __shared__ __align__(16) char lsb[2][16384];   // B tile [128][64] bf16

    const int tid = threadIdx.x;
    const int lane = tid & 63;
    const int w = tid >> 6;
    const int wr = w >> 1, wc = w & 1;

    // XCD-aware bijective swizzle (T1): all launches have nwg % 8 == 0.
    int wg = blockIdx.y * gridDim.x + blockIdx.x;
    const int nwg = gridDim.x * gridDim.y;
    wg = (wg & 7) * (nwg >> 3) + (wg >> 3);
    const int bx = wg % gridDim.x, by = wg / gridDim.x;
    const int row0 = by * 64, col0 = bx * 128;

    const int rl = lane & 15, q = lane >> 4;

    const char* gA[2];
#pragma unroll
    for (int j = 0; j < 2; ++j) {
        int L = SWZ((w * 2 + j) * 1024 + lane * 16);
        gA[j] = (const char*)A + ((size_t)(row0 + (L >> 7)) * K) * 2 + (L & 127);
    }
    const char* gB[4];
#pragma unroll
    for (int j = 0; j < 4; ++j) {
        int L = SWZ((w * 4 + j) * 1024 + lane * 16);
        gB[j] = (const char*)Bt + ((size_t)(col0 + (L >> 7)) * K) * 2 + (L & 127);
    }

    int LA[2][2], LB[4][2];
#pragma unroll
    for (int m = 0; m < 2; ++m)
#pragma unroll
        for (int kk = 0; kk < 2; ++kk)
            LA[m][kk] = SWZ((wr * 32 + m * 16 + rl) * 128 + kk * 64 + q * 16);
#pragma unroll
    for (int n = 0; n < 4; ++n)
#pragma unroll
        for (int kk = 0; kk < 2; ++kk)
            LB[n][kk] = SWZ((wc * 64 + n * 16 + rl) * 128 + kk * 64 + q * 16);

    f32x4 acc[2][4] = {};
    const int NT = K >> 6;   // BK = 64

#pragma unroll
    for (int j = 0; j < 2; ++j) gl_lds16(gA[j], &lsa[0][(w * 2 + j) * 1024]);
#pragma unroll
    for (int j = 0; j < 4; ++j) gl_lds16(gB[j], &lsb[0][(w * 4 + j) * 1024]);

    int cur = 0;
    for (int kt = 0; kt < NT; ++kt) {
        if (kt + 1 < NT) {
            const int kb = (kt + 1) * 128;
#pragma unroll
            for (int j = 0; j < 2; ++j)
                gl_lds16(gA[j] + kb, &lsa[cur ^ 1][(w * 2 + j) * 1024]);
#pragma unroll
            for (int j = 0; j < 4; ++j)
                gl_lds16(gB[j] + kb, &lsb[cur ^ 1][(w * 4 + j) * 1024]);
            asm volatile("s_waitcnt vmcnt(6)\n\ts_barrier" ::: "memory");
        } else {
            asm volatile("s_waitcnt vmcnt(0)\n\ts_barrier" ::: "memory");
        }
        short8 af[2][2], bfr[4][2];
#pragma unroll
        for (int m = 0; m < 2; ++m)
#pragma unroll
            for (int kk = 0; kk < 2; ++kk)
                af[m][kk] = *(const short8*)(&lsa[cur][LA[m][kk]]);
#pragma unroll
        for (int n = 0; n < 4; ++n)
#pragma unroll
            for (int kk = 0; kk < 2; ++kk)
                bfr[n][kk] = *(const short8*)(&lsb[cur][LB[n][kk]]);
#pragma unroll
        for (int kk = 0; kk < 2; ++kk)
#pragma unroll
            for (int m = 0; m < 2; ++m)
#pragma unroll
                for (int n = 0; n < 4; ++n)
                    acc[m][n] = __builtin_amdgcn_mfma_f32_16x16x32_bf16(
                        af[m][kk], bfr[n][kk], acc[m][n], 0, 0, 0);
        asm volatile("s_barrier" ::: "memory");
        cur ^= 1;
    }

    float bia[4];
#pragma unroll
    for (int n = 0; n < 4; ++n) {
        int c = col0 + wc * 64 + n * 16 + rl;
        bia[n] = (HAS_BIAS && c < DM) ? bias[c] : 0.f;
    }
#pragma unroll
    for (int m = 0; m < 2; ++m) {
#pragma unroll
        for (int n = 0; n < 4; ++n) {
            int c = col0 + wc * 64 + n * 16 + rl;
#pragma unroll
            for (int i = 0; i < 4; ++i) {
                int r = row0 + wr * 32 + m * 16 + q * 4 + i;
                float v = acc[m][n][i];
                if (PROJMODE == 1 && c >= DM) {
                    if (c < DM + DS)          BpO[(size_t)r * DS + (c - DM)] = v;
                    else if (c < DM + 2 * DS) CpO[(size_t)r * DS + (c - DM - DS)] = v;
                } else if (PROJMODE == 2 && c >= DM) {
                    if (c == DM) BpO[r] = v;
                } else {
                    v += bia[n];
                    if (ACT == 1) v = sp_f(v);
                    if (HAS_RES) v += res[(size_t)r * ldc + c];
                    if (OUTBF) ((ushort_t*)Cout)[(size_t)r * ldc + c] = f2bf(v);
                    else       ((float*)Cout)[(size_t)r * ldc + c] = v;
                }
            }
        }
    }
}

// ---------------------------------------------------------------------------
// Merged prep kernel (region-branched on blockIdx.x)
// ---------------------------------------------------------------------------
static __device__ __forceinline__ void tconv_body(
    const float* __restrict__ in, ushort_t* __restrict__ out,
    int K, int N, int n0, int k0, float (*t)[33], int tid)
{
    int lx = tid & 31, ly = tid >> 5;
#pragma unroll
    for (int i = 0; i < 32; i += 8)
        t[ly + i][lx] = in[(size_t)(k0 + ly + i) * N + n0 + lx];
    __syncthreads();
#pragma unroll
    for (int i = 0; i < 32; i += 8)
        out[(size_t)(n0 + ly + i) * K + k0 + lx] = f2bf(t[lx][ly + i]);
}

__global__ __launch_bounds__(256) void prep_k(
    const float* __restrict__ x, const float* __restrict__ W_in,
    const float* __restrict__ W_B, const float* __restrict__ W_C,
    const float* __restrict__ W_delta, const float* __restrict__ db,
    const float* __restrict__ W_tau, const float* __restrict__ W_out,
    ushort_t* __restrict__ x_bf, ushort_t* __restrict__ WinT,
    ushort_t* __restrict__ WtT, ushort_t* __restrict__ WoT,
    ushort_t* __restrict__ WdX, ushort_t* __restrict__ WdcT)
{
    __shared__ float t[32][33];
    const int blk = blockIdx.x;
    const int tid = threadIdx.x;
    if (blk < 2048) {
        int i = blk * 256 + tid;
        f4 v = ((const f4*)x)[i];
        us4 o; o.x = f2bf(v.x); o.y = f2bf(v.y); o.z = f2bf(v.z); o.w = f2bf(v.w);
        ((us4*)x_bf)[i] = o;
    } else if (blk < 3072) {
        int i = (blk - 2048) * 256 + tid;
        f4 v = ((const f4*)W_delta)[i];
        us4 o; o.x = f2bf(v.x); o.y = f2bf(v.y); o.z = f2bf(v.z); o.w = f2bf(v.w);
        ((us4*)WdX)[i] = o;
    } else if (blk < 3584) {
        int i = (blk - 3072) * 256 + tid;       // 0..131071
        int k = i & 1023, r = i >> 10;          // r 0..127
        WdX[(size_t)(1024 + r) * 1024 + k] = (r == 0) ? f2bf(db[k]) : (ushort_t)0;
    } else if (blk < 5632) {
        int tau = blk - 3584;
        tconv_body(W_in, WinT, 1024, 2048, (tau & 63) * 32, (tau >> 6) * 32, t, tid);
    } else if (blk < 6656) {
        int tau = blk - 5632;
        tconv_body(W_tau, WtT, 1024, 1024, (tau & 31) * 32, (tau >> 5) * 32, t, tid);
    } else if (blk < 7680) {
        int tau = blk - 6656;
        tconv_body(W_out, WoT, 1024, 1024, (tau & 31) * 32, (tau >> 5) * 32, t, tid);
    } else {
        int i = (blk - 7680) * 256 + tid;       // 0..131071
        int k = i & 1023, r = i >> 10;          // r 0..127
        ushort_t v = 0;
        if (r < DS)          v = f2bf(W_B[(size_t)k * DS + r]);
        else if (r < 2 * DS) v = f2bf(W_C[(size_t)k * DS + (r - DS)]);
        WdcT[(size_t)(1024 + r) * 1024 + k] = v;
    }
}

// ---------------------------------------------------------------------------
// Depthwise conv1d (K=3, same padding) + SiLU.  bf16 in (z), bf16 out (val).
// ---------------------------------------------------------------------------
__global__ __launch_bounds__(256) void conv_silu_k(
    const ushort_t* __restrict__ z_bf, const float* __restrict__ cw,
    ushort_t* __restrict__ val_bf)
{
    int t = blockIdx.x * 256 + threadIdx.x;    // ROWS*DI/4
    int c0 = (t & 255) * 4;
    int row = t >> 8;
    int l = row & (LL - 1);
    const ushort_t* zr = z_bf + (size_t)row * (2 * DI) + c0;
    us4 zz = {0, 0, 0, 0};
    us4 vm = (l > 0)      ? *(const us4*)(zr - 2 * DI) : zz;
    us4 v0 = *(const us4*)(zr);
    us4 vp = (l < LL - 1) ? *(const us4*)(zr + 2 * DI) : zz;
    const f4* wp = (const f4*)(cw + (size_t)c0 * 3);
    f4 w0 = wp[0], w1 = wp[1], w2 = wp[2];
    float w[12];
#pragma unroll
    for (int k = 0; k < 4; ++k) { w[k] = w0[k]; w[4 + k] = w1[k]; w[8 + k] = w2[k]; }
    us4 o;
#pragma unroll
    for (int j = 0; j < 4; ++j) {
        float s = bf2f(vm[j]) * w[3 * j] + bf2f(v0[j]) * w[3 * j + 1]
                + bf2f(vp[j]) * w[3 * j + 2];
        float si = s / (1.f + __expf(-s));
        o[j] = f2bf(si);
    }
    *(us4*)(val_bf + (size_t)row * DI + c0) = o;
}

// ---------------------------------------------------------------------------
// Fused selective scan (p1+p2+p3 in one kernel, chunk state in LDS).
// Block = (b, 4 consecutive d), 256 threads: thread (d_sub=tid&3, c=tid>>2)
// owns chunk c of chain d.  Phase A: local chunk scan (h_in=0) -> LDS.
// Phase B (wave 0): 64 chains x serial 64-chunk combine in LDS -> hin.
// Phase C: recompute with correct h_in, fused gate -> g_bf.
// LDS slot layout XOR-swizzled so phase A/C f4 ops are bank-conflict-free.
// ---------------------------------------------------------------------------
static __device__ __forceinline__ int slot4(int t, int j) {
    return t * 64 + 16 * (j ^ ((t >> 1) & 3));
}

__global__ __launch_bounds__(256) void scan_f_k(
    const ushort_t* __restrict__ Del_bf, const ushort_t* __restrict__ val_bf,
    const float* __restrict__ Bp, const float* __restrict__ Cp,
    const float* __restrict__ A_log, const ushort_t* __restrict__ z_bf,
    ushort_t* __restrict__ g_bf)
{
    __shared__ __align__(16) char lap[16384];   // aprod, then hin (in place)
    __shared__ __align__(16) char lhl[16384];   // hloc

    const int tid = threadIdx.x;
    const int d_sub = tid & 3, c = tid >> 2;    // c = 0..63
    const int b = blockIdx.x >> 8;
    const int d = (blockIdx.x & 255) * 4 + d_sub;

    float Adn[DS], ci[DS];
    const f4* alp = (const f4*)(A_log + (size_t)d * DS);
#pragma unroll
    for (int j = 0; j < 4; ++j) {
        f4 al = alp[j];
#pragma unroll
        for (int k = 0; k < 4; ++k) {
            float a = -__expf(al[k]);
            Adn[j * 4 + k] = a;
            ci[j * 4 + k] = 1.0f / a;
        }
    }
    const int row0 = b * LL + c * CH;
    const ushort_t* Dp = Del_bf + (size_t)row0 * DI + d;
    const ushort_t* up = val_bf + (size_t)row0 * DI + d;
    const ushort_t* zp = z_bf + (size_t)row0 * (2 * DI) + DI + d;
    const f4* bp = (const f4*)(Bp + (size_t)row0 * DS);
    const f4* cp = (const f4*)(Cp + (size_t)row0 * DS);
    ushort_t* gp = g_bf + (size_t)row0 * DI + d;

    // ---- Phase A: local chunk scan with h_in = 0 ----
    float h[DS];
#pragma unroll
    for (int n = 0; n < DS; ++n) h[n] = 0.f;
    float sdv = 0.f;
#pragma unroll 2
    for (int l = 0; l < CH; ++l) {
        float dv = bf2f(Dp[(size_t)l * DI]);
        float u  = bf2f(up[(size_t)l * DI]);
        f4 q0 = bp[l * 4 + 0], q1 = bp[l * 4 + 1], q2 = bp[l * 4 + 2], q3 = bp[l * 4 + 3];
        float bn[DS];
#pragma unroll
        for (int k = 0; k < 4; ++k) {
            bn[k] = q0[k]; bn[4 + k] = q1[k]; bn[8 + k] = q2[k]; bn[12 + k] = q3[k];
        }
        sdv += dv;
#pragma unroll
        for (int n = 0; n < DS; ++n) {
            float a  = __expf(dv * Adn[n]);
            float tt = (ci[n] * bn[n]) * u;
            float s  = h[n] + tt;
            h[n] = fmaf(a, s, -tt);
        }
    }
#pragma unroll
    for (int j = 0; j < 4; ++j) {
        f4 hv, av;
#pragma unroll
        for (int k = 0; k < 4; ++k) {
            hv[k] = h[j * 4 + k];
            av[k] = __expf(sdv * Adn[j * 4 + k]);
        }
        *(f4*)(lap + slot4(tid, j)) = av;
        *(f4*)(lhl + slot4(tid, j)) = hv;
    }
    __syncthreads();

    // ---- Phase B (wave 0): per-chain serial combine over 64 chunks ----
    if (tid < 64) {
        int ds2 = tid >> 4, n = tid & 15;
        int jj = n >> 2, ee = 4 * (n & 3);
        float h2 = 0.f;
#pragma unroll 8
        for (int c2 = 0; c2 < NCH; ++c2) {
            int off = slot4(c2 * 4 + ds2, jj) + ee;
            float ap = *(const float*)(lap + off);
            float hl = *(const float*)(lhl + off);
            *(float*)(lap + off) = h2;           // hin (overwrites aprod)
            h2 = fmaf(ap, h2, hl);
        }
    }
    __syncthreads();

    // ---- Phase C: recompute with correct h_in; fused gate ----
#pragma unroll
    for (int j = 0; j < 4; ++j) {
        f4 hv = *(const f4*)(lap + slot4(tid, j));
#pragma unroll
        for (int k = 0; k < 4; ++k) h[j * 4 + k] = hv[k];
    }
#pragma unroll 2
    for (int l = 0; l < CH; ++l) {
        float dv = bf2f(Dp[(size_t)l * DI]);
        float u  = bf2f(up[(size_t)l * DI]);
        f4 q0 = bp[l * 4 + 0], q1 = bp[l * 4 + 1], q2 = bp[l * 4 + 2], q3 = bp[l * 4 + 3];
        f4 r0 = cp[l * 4 + 0], r1 = cp[l * 4 + 1], r2 = cp[l * 4 + 2], r3 = cp[l * 4 + 3];
        float bn[DS], cn[DS];
#pragma unroll
        for (int k = 0; k < 4; ++k) {
            bn[k] = q0[k]; bn[4 + k] = q1[k]; bn[8 + k] = q2[k]; bn[12 + k] = q3[k];
            cn[k] = r0[k]; cn[4 + k] = r1[k]; cn[8 + k] = r2[k]; cn[12 + k] = r3[k];
        }
        float psum = 0.f;
#pragma unroll
        for (int n = 0; n < DS; ++n) {
            float a  = __expf(dv * Adn[n]);
            float tt = (ci[n] * bn[n]) * u;
            float s  = h[n] + tt;
            h[n] = fmaf(a, s, -tt);
            psum = fmaf(h[n], cn[n], psum);
        }
        float zg = bf2f(zp[(size_t)l * 2 * DI]);
        float si = zg / (1.f + __expf(-zg));
        gp[(size_t)l * DI] = f2bf(psum * si);
    }
}

// ---------------------------------------------------------------------------
extern "C" void kernel_launch(void* const* d_in, const int* in_sizes, int n_in,
                              void* d_out, int out_size, void* d_ws, size_t ws_size,
                              hipStream_t stream)
{
    (void)in_sizes; (void)n_in; (void)out_size; (void)ws_size;

    const float* x        = (const float*)d_in[0];
    const float* W_in     = (const float*)d_in[1];
    const float* conv_w   = (const float*)d_in[2];
    const float* W_B      = (const float*)d_in[3];
    const float* W_C      = (const float*)d_in[4];
    const float* W_delta  = (const float*)d_in[5];
    const float* delta_b  = (const float*)d_in[6];
    const float* W_tau    = (const float*)d_in[7];
    const float* A_log    = (const float*)d_in[8];
    const float* W_out    = (const float*)d_in[9];
    float* out = (float*)d_out;

    const size_t M1 = 1024 * 1024;
    ushort_t* us = (ushort_t*)d_ws;
    ushort_t* z_bf   = us;                    // 4M ushort
    ushort_t* val_bf = us + 4 * M1;           // 2M
    ushort_t* Del_bf = us + 6 * M1;           // 2M
    ushort_t* x_bf   = us + 8 * M1;           // 2M
    ushort_t* g_bf   = us + 10 * M1;          // 2M
    ushort_t* WinT   = us + 12 * M1;          // 2M
    ushort_t* WoT    = us + 14 * M1;          // 1M
    ushort_t* WtT    = us + 15 * M1;          // 1M
    ushort_t* WdX    = us + 16 * M1;          // NF*1024
    ushort_t* WdcT   = WdX + (size_t)NF * 1024;   // NP*1024 (~38.3MB end)
    float* fb    = (float*)(us + 20 * M1);    // 40MB offset
    float* Bp    = fb;                         // 32768
    float* Cp    = fb + (size_t)ROWS * DS;     // 32768
    float* b2    = fb + 2 * (size_t)ROWS * DS; // 1024

    // 0) merged prep: converts, transposes, tail rows
    prep_k<<<8192, 256, 0, stream>>>(x, W_in, W_B, W_C, W_delta, delta_b,
                                     W_tau, W_out, x_bf, WinT, WtT, WoT, WdX, WdcT);

    // 0b) fused weight: WdcT[n][i] = sum_m WtT[n][m]*WdX[i][m]; col 1024 -> b2
    gemm_bf_k<0, false, false, true, 2><<<dim3(NF / 128, DM / 64), 256, 0, stream>>>(
        WtT, WdX, nullptr, nullptr, WdcT, b2, nullptr, DM, NF, DM, DM);

    // 1) z = x @ W_in  (bf16 out)
    gemm_bf_k<0, false, false, true, 0><<<dim3(2 * DI / 128, ROWS / 64), 256, 0, stream>>>(
        x_bf, WinT, nullptr, nullptr, z_bf, nullptr, nullptr, ROWS, 2 * DI, DM, 2 * DI);

    // 2) val = silu(conv1d(z[:, :DI]))
    conv_silu_k<<<(ROWS * DI / 4) / 256, 256, 0, stream>>>(z_bf, conv_w, val_bf);

    // 3) Delta = softplus(val @ Wfused + b2) -> Del_bf; fused B/C proj -> Bp,Cp
    gemm_bf_k<1, true, false, true, 1><<<dim3(NP / 128, ROWS / 64), 256, 0, stream>>>(
        val_bf, WdcT, b2, nullptr, Del_bf, Bp, Cp, ROWS, NP, DI, DM);

    // 4) fused selective scan (p1+p2+p3 + gate) -> g_bf
    scan_f_k<<<BB * (DI / 4), 256, 0, stream>>>(
        Del_bf, val_bf, Bp, Cp, A_log, z_bf, g_bf);

    // 5) out = g @ W_out + x (fp32 out)
    gemm_bf_k<0, false, true, false, 0><<<dim3(DM / 128, ROWS / 64), 256, 0, stream>>>(
        g_bf, WoT, nullptr, x, out, nullptr, nullptr, ROWS, DM, DI, DM);
}